// Round 13
// baseline (154.138 us; speedup 1.0000x reference)
//
#include <hip/hip_runtime.h>
#include <math.h>

// Fbank via split-bf16 MFMA + real-DFT folding. R13 = R12 with the DC-mean
// folded OUT of the GEMM as a rank-1 correction: real = R~ - mc*C[f],
// imag = I~ - mc*S[f], C/S precomputed in prep from win x dft tables.
// Eliminates the separate mean pre-pass (waveform read once, not twice);
// mean is accumulated as a by-product of the pack loads and applied in fp32
// at the power phase.

#define BATCH 32
#define TLEN 480000
#define NFRAMES 2998
#define FL 400
#define FS 160
#define PW 512
#define NM 80
#define MT 32                // frames per block
#define NTILES 94            // ceil(2998/32)
#define PRE 0.97f
#define EPSF 1e-6f

#define RE_KS 9              // K=288 (t 0..256 + pad)
#define IM_KS 8              // K=256 (t 0..255)
#define RE_U16 (16 * RE_KS * 64 * 8)   // 73728
#define IM_U16 (16 * IM_KS * 64 * 8)   // 65536
#define MEL_U16 (6 * 8 * 64 * 8)       // 24576
#define OFF_REH 0
#define OFF_REL RE_U16
#define OFF_IMH (2 * RE_U16)
#define OFF_IML (2 * RE_U16 + IM_U16)
#define OFF_MEL (2 * RE_U16 + 2 * IM_U16)
#define OFF_CS  (OFF_MEL + MEL_U16)          // u16 units; 512 floats follow
#define WS_NEED ((size_t)OFF_CS * 2 + 512 * 4)   // ~608 KB

// LDS tile byte offsets. 128-col tiles: 272-B row stride (natural bank
// rotation, no XOR). 160-col chunk1 s-tile: 320-B stride + SWT1 XOR.
#define C0_SH 0
#define C0_SL 8704
#define C0_DH 17408
#define C0_DL 26112          // chunk0 total 34,816 B
#define C1_SH 0
#define C1_SL 10240
#define C1_DH 20480
#define C1_DL 29184          // chunk1 total 37,888 B

typedef short bf16x8 __attribute__((ext_vector_type(8)));
typedef float f32x4 __attribute__((ext_vector_type(4)));
typedef unsigned int u32;
typedef unsigned short u16;
typedef u32 u32x4 __attribute__((ext_vector_type(4)));

__device__ __forceinline__ u16 f2bf(float f) {
    u32 u = __builtin_bit_cast(u32, f);
    return (u16)((u + 0x7FFFu + ((u >> 16) & 1u)) >> 16);
}
__device__ __forceinline__ float bf2f(u16 h) {
    u32 u = ((u32)h) << 16;
    return __builtin_bit_cast(float, u);
}

// ---------------- prep: folded B (cos/sin hi+lo), mel, and C/S correction ----------------
__global__ void prep_kernel(const float* __restrict__ dftr, const float* __restrict__ dfti,
                            const float* __restrict__ melw, const float* __restrict__ win,
                            u16* __restrict__ wsb) {
    int idx = blockIdx.x * 256 + threadIdx.x;
    if (idx < 16 * RE_KS * 64) {                       // 9216 Re groups
        int nf = idx / (RE_KS * 64);
        int rem = idx - nf * (RE_KS * 64);
        int ks = rem >> 6, l = rem & 63;
        int f = nf * 16 + (l & 15);
        int k = ks * 32 + ((l >> 4) << 3);
        u16* dh = wsb + OFF_REH + (size_t)idx * 8;
        u16* dl = wsb + OFF_REL + (size_t)idx * 8;
        #pragma unroll
        for (int e = 0; e < 8; ++e) {
            int kk = k + e;
            float x = (kk <= 256) ? dftr[(size_t)f * PW + kk] : 0.f;
            u16 h = f2bf(x);
            dh[e] = h;
            dl[e] = f2bf(x - bf2f(h));
        }
    } else if (idx < 16 * RE_KS * 64 + 16 * IM_KS * 64) {   // 8192 Im groups
        int j = idx - 16 * RE_KS * 64;
        int nf = j / (IM_KS * 64);
        int rem = j - nf * (IM_KS * 64);
        int ks = rem >> 6, l = rem & 63;
        int f = nf * 16 + (l & 15);
        int k = ks * 32 + ((l >> 4) << 3);
        u16* dh = wsb + OFF_IMH + (size_t)j * 8;
        u16* dl = wsb + OFF_IML + (size_t)j * 8;
        #pragma unroll
        for (int e = 0; e < 8; ++e) {
            float x = dfti[(size_t)f * PW + k + e];    // k+e <= 255
            u16 h = f2bf(x);
            dh[e] = h;
            dl[e] = f2bf(x - bf2f(h));
        }
    } else if (idx < 16 * RE_KS * 64 + 16 * IM_KS * 64 + 6 * 8 * 64) {  // mel
        int m = idx - (16 * RE_KS * 64 + 16 * IM_KS * 64);
        int nf = m / (8 * 64);
        int ks = (m >> 6) & 7, l = m & 63;
        int n = nf * 16 + (l & 15);
        int k = ks * 32 + ((l >> 4) << 3);
        u16* dst = wsb + OFF_MEL + (size_t)m * 8;
        #pragma unroll
        for (int e = 0; e < 8; ++e)
            dst[e] = (n < NM) ? f2bf(melw[(size_t)n * 257 + k + e]) : (u16)0;
    } else {                                            // 512 C/S entries
        int f = idx - (16 * RE_KS * 64 + 16 * IM_KS * 64 + 6 * 8 * 64);
        if (f < 512) {
            float* cs = (float*)(wsb + OFF_CS);
            if (f < 256) {
                float acc = 0.f;
                for (int t = 0; t <= 256; ++t) {
                    float wt = (t < FL) ? win[t] : 0.f;
                    float wu = (t >= 1 && t < 256 && (512 - t) < FL) ? win[512 - t] : 0.f;
                    acc += (wt + wu) * dftr[(size_t)f * PW + t];
                }
                cs[f] = acc;
            } else {
                int ff = f - 256;
                float acc = 0.f;
                for (int t = 0; t <= 255; ++t) {
                    float wt = (t < FL) ? win[t] : 0.f;
                    float wu = (t >= 1 && (512 - t) < FL) ? win[512 - t] : 0.f;
                    acc += (wt - wu) * dfti[(size_t)ff * PW + t];
                }
                cs[256 + ff] = acc;
            }
        }
    }
}

// swizzle select: 0 -> (r&7)<<4 (512-B stride), 1 -> ((r>>1)&3)<<4 (320-B), 2 -> none (272-B)
__device__ __forceinline__ u32 swz(int SWT, u32 r) {
    return (SWT == 0) ? ((r & 7u) << 4) : (SWT == 1) ? (((r >> 1) & 3u) << 4) : 0u;
}

// 6 MFMA for one (bh,bl) ping-pong slot: 2 m-frags x 3 split-product terms
#define MFMA6(D, J)                                                                        \
    _Pragma("unroll")                                                                      \
    for (int mf = 0; mf < 2; ++mf) {                                                       \
        acc[mf][J] = __builtin_amdgcn_mfma_f32_16x16x32_bf16(aH[mf], D[0], acc[mf][J], 0, 0, 0); \
        acc[mf][J] = __builtin_amdgcn_mfma_f32_16x16x32_bf16(aL[mf], D[0], acc[mf][J], 0, 0, 0); \
        acc[mf][J] = __builtin_amdgcn_mfma_f32_16x16x32_bf16(aH[mf], D[1], acc[mf][J], 0, 0, 0); \
    }

// ---------------- DFT pass: split product, B ping-pong prefetch ----------------
template<int RS, int SWT, int NKS, int BKS>
__device__ __forceinline__ void dft_pass(
    const char* tH, const char* tL,
    const u16* __restrict__ bH, const u16* __restrict__ bL,
    int ks0, int g, int lane, f32x4 (&acc)[2][4]) {

    bf16x8 aH[2], aL[2], Ba[2], Bb[2];

#define LDA_P(KS)                                                              \
    { _Pragma("unroll")                                                        \
      for (int mf = 0; mf < 2; ++mf) {                                         \
        u32 r = (u32)(mf * 16 + (lane & 15));                                  \
        u32 off = (u32)((KS) * 64 + ((lane >> 4) << 4));                       \
        u32 byte = r * RS + (off ^ swz(SWT, r));                               \
        aH[mf] = *(const bf16x8*)(tH + byte);                                  \
        aL[mf] = *(const bf16x8*)(tL + byte);                                  \
      } }
#define LDB_P(KSG, J, D)                                                       \
    {                                                                          \
        size_t o = ((size_t)((4 * g + (J)) * BKS + (KSG)) * 64 + lane) * 8;    \
        D[0] = *(const bf16x8*)(bH + o);                                       \
        D[1] = *(const bf16x8*)(bL + o);                                       \
    }

    LDB_P(ks0, 0, Ba);
    #pragma unroll
    for (int ks = 0; ks < NKS; ++ks) {
        LDA_P(ks);
        LDB_P(ks0 + ks, 1, Bb);
        MFMA6(Ba, 0);
        LDB_P(ks0 + ks, 2, Ba);
        MFMA6(Bb, 1);
        LDB_P(ks0 + ks, 3, Bb);
        MFMA6(Ba, 2);
        if (ks + 1 < NKS) LDB_P(ks0 + ks + 1, 0, Ba);
        MFMA6(Bb, 3);
    }
#undef LDA_P
#undef LDB_P
}

__device__ __forceinline__ void pack_write(const float* ys, char* baseH, char* baseL, u32 byte) {
    u32x4 hv, lv;
    #pragma unroll
    for (int e = 0; e < 4; ++e) {
        u16 h0 = f2bf(ys[2 * e]), h1 = f2bf(ys[2 * e + 1]);
        hv[e] = (u32)h0 | ((u32)h1 << 16);
        u16 l0 = f2bf(ys[2 * e] - bf2f(h0)), l1 = f2bf(ys[2 * e + 1] - bf2f(h1));
        lv[e] = (u32)l0 | ((u32)l1 << 16);
    }
    *(u32x4*)(baseH + byte) = hv;
    *(u32x4*)(baseL + byte) = lv;
}

// ---------------- main fused kernel ----------------
__global__ __launch_bounds__(256, 3) void fbank_mfma(
    const float* __restrict__ wave, const float* __restrict__ win,
    const u16* __restrict__ wsb, float* __restrict__ out) {
    __shared__ float smean[MT];
    __shared__ u16 stile[18944];       // 37,888 B tile buffer (power overlay fits)
    char* T = (char*)stile;

    const int tid = threadIdx.x, w = tid >> 6, lane = tid & 63;
    const int q = lane >> 4;           // frame sub-row within step
    const int cg = lane & 15;          // col-group
    const int b = blockIdx.y;
    const int f0 = blockIdx.x * MT;
    const float* wb = wave + (size_t)b * TLEN;
    const float4* win4 = (const float4*)win;

    float ps[2] = {0.f, 0.f};          // per-frame waveform partial sums (for mean)

    // ---- P1b: chunk0 (t 0..127): build x-only s,d tiles (272-B stride, no XOR) ----
    #pragma unroll
    for (int i = 0; i < 2; ++i) {
        const int rr = w * 8 + i * 4 + q;
        const int fr = f0 + rr;
        const bool valid = fr < NFRAMES;
        const float* x = wb + (size_t)fr * FS;
        const float4* x4 = (const float4*)x;

        float4 v0 = {0,0,0,0}, v1 = {0,0,0,0};
        if (valid) { v0 = x4[2 * cg]; v1 = x4[2 * cg + 1]; }
        ps[i] += v0.x + v0.y + v0.z + v0.w + v1.x + v1.y + v1.z + v1.w;
        float4 w0 = win4[2 * cg], w1 = win4[2 * cg + 1];
        float xpn = __shfl(v1.w, lane - 1);
        float xprev = (cg == 0) ? v0.x : xpn;
        float y[8];
        y[0] = (v0.x - PRE * xprev) * w0.x;
        y[1] = (v0.y - PRE * v0.x) * w0.y;
        y[2] = (v0.z - PRE * v0.y) * w0.z;
        y[3] = (v0.w - PRE * v0.z) * w0.w;
        y[4] = (v1.x - PRE * v0.w) * w1.x;
        y[5] = (v1.y - PRE * v1.x) * w1.y;
        y[6] = (v1.z - PRE * v1.y) * w1.z;
        y[7] = (v1.w - PRE * v1.z) * w1.w;

        float yr[8];
        #pragma unroll
        for (int e = 0; e < 8; ++e) yr[e] = 0.f;
        if (cg >= 14) {                      // t >= 113 folds (u = 512-t in 385..399)
            const int u0 = 512 - 8 * cg;     // 400 (cg14) or 392 (cg15)
            float4 xr0 = {0,0,0,0}, xr1 = {0,0,0,0};
            float xu0 = 0.f;
            if (valid) {
                xr0 = x4[u0 / 4 - 2]; xr1 = x4[u0 / 4 - 1];
                if (u0 <= 399) xu0 = x[u0];
            }
            ps[i] += xr0.x + xr0.y + xr0.z + xr0.w + xr1.x + xr1.y + xr1.z + xr1.w;
            float4 wr0 = win4[u0 / 4 - 2], wr1 = win4[u0 / 4 - 1];
            float wu0 = (u0 <= 399) ? win[u0] : 0.f;
            yr[0] = (xu0   - PRE * xr1.w) * wu0;
            yr[1] = (xr1.w - PRE * xr1.z) * wr1.w;
            yr[2] = (xr1.z - PRE * xr1.y) * wr1.z;
            yr[3] = (xr1.y - PRE * xr1.x) * wr1.y;
            yr[4] = (xr1.x - PRE * xr0.w) * wr1.x;
            yr[5] = (xr0.w - PRE * xr0.z) * wr0.w;
            yr[6] = (xr0.z - PRE * xr0.y) * wr0.z;
            yr[7] = (xr0.y - PRE * xr0.x) * wr0.y;
        }
        float s8[8], d8[8];
        #pragma unroll
        for (int e = 0; e < 8; ++e) { s8[e] = y[e] + yr[e]; d8[e] = y[e] - yr[e]; }
        u32 byte = (u32)rr * 272u + (u32)cg * 16u;
        pack_write(s8, T + C0_SH, T + C0_SL, byte);
        pack_write(d8, T + C0_DH, T + C0_DL, byte);
    }
    __syncthreads();

    // ---- GEMM chunk0: Re ks 0..3 (A=s), Im ks 0..3 (A=d) ----
    const int g = w;
    f32x4 accR[2][4], accI[2][4];
    #pragma unroll
    for (int mf = 0; mf < 2; ++mf)
        #pragma unroll
        for (int j = 0; j < 4; ++j) { accR[mf][j] = (f32x4)0.f; accI[mf][j] = (f32x4)0.f; }

    dft_pass<272, 2, 4, RE_KS>(T + C0_SH, T + C0_SL, wsb + OFF_REH, wsb + OFF_REL, 0, g, lane, accR);
    dft_pass<272, 2, 4, IM_KS>(T + C0_DH, T + C0_DL, wsb + OFF_IMH, wsb + OFF_IML, 0, g, lane, accI);
    __syncthreads();

    // ---- P1c: chunk1 (t 128..255 fold; s also t 256..287 tail) ----
    #pragma unroll
    for (int i = 0; i < 2; ++i) {
        const int rr = w * 8 + i * 4 + q;
        const int fr = f0 + rr;
        const bool valid = fr < NFRAMES;
        const float* x = wb + (size_t)fr * FS;
        const float4* x4 = (const float4*)x;

        float4 v0 = {0,0,0,0}, v1 = {0,0,0,0};
        if (valid) { v0 = x4[32 + 2 * cg]; v1 = x4[33 + 2 * cg]; }
        ps[i] += v0.x + v0.y + v0.z + v0.w + v1.x + v1.y + v1.z + v1.w;
        float4 w0 = win4[32 + 2 * cg], w1 = win4[33 + 2 * cg];
        float xpn = __shfl(v1.w, lane - 1);
        float xprev = (cg == 0) ? (valid ? x[127] : 0.f) : xpn;
        float y[8];
        y[0] = (v0.x - PRE * xprev) * w0.x;
        y[1] = (v0.y - PRE * v0.x) * w0.y;
        y[2] = (v0.z - PRE * v0.y) * w0.z;
        y[3] = (v0.w - PRE * v0.z) * w0.w;
        y[4] = (v1.x - PRE * v0.w) * w1.x;
        y[5] = (v1.y - PRE * v1.x) * w1.y;
        y[6] = (v1.z - PRE * v1.y) * w1.z;
        y[7] = (v1.w - PRE * v1.z) * w1.w;

        const int u0 = 384 - 8 * cg;        // 264..384, all fold
        float4 xr0 = {0,0,0,0}, xr1 = {0,0,0,0};
        float xu0 = 0.f;
        if (valid) { xr0 = x4[u0 / 4 - 2]; xr1 = x4[u0 / 4 - 1]; xu0 = x[u0]; }
        ps[i] += xr0.x + xr0.y + xr0.z + xr0.w + xr1.x + xr1.y + xr1.z + xr1.w;
        float4 wr0 = win4[u0 / 4 - 2], wr1 = win4[u0 / 4 - 1];
        float wu0 = win[u0];
        float yr[8];
        yr[0] = (xu0   - PRE * xr1.w) * wu0;
        yr[1] = (xr1.w - PRE * xr1.z) * wr1.w;
        yr[2] = (xr1.z - PRE * xr1.y) * wr1.z;
        yr[3] = (xr1.y - PRE * xr1.x) * wr1.y;
        yr[4] = (xr1.x - PRE * xr0.w) * wr1.x;
        yr[5] = (xr0.w - PRE * xr0.z) * wr0.w;
        yr[6] = (xr0.z - PRE * xr0.y) * wr0.z;
        yr[7] = (xr0.y - PRE * xr0.x) * wr0.y;

        float s8[8], d8[8];
        #pragma unroll
        for (int e = 0; e < 8; ++e) { s8[e] = y[e] + yr[e]; d8[e] = y[e] - yr[e]; }
        u32 byteS = (u32)rr * 320u + (((u32)cg * 16u) ^ ((((u32)rr >> 1) & 3u) << 4));
        u32 byteD = (u32)rr * 272u + (u32)cg * 16u;
        pack_write(s8, T + C1_SH, T + C1_SL, byteS);
        pack_write(d8, T + C1_DH, T + C1_DL, byteD);

        // finalize mean for this frame (samples 0..399 covered exactly once)
        float acc = ps[i];
        #pragma unroll
        for (int o = 8; o; o >>= 1) acc += __shfl_xor(acc, o);
        if (cg == 0) smean[rr] = acc * (1.0f / FL);
    }
    // s tail: cols t=256..287 (units 16..19): only t=256 nonzero (x-only)
    {
        const int rr = tid & 31;
        const int grp = tid >> 5;          // 0..7; units 16..19 served by grp<4
        if (grp < 4) {
            const int fr = f0 + rr;
            float y256 = 0.f;
            if (grp == 0 && fr < NFRAMES) {
                const float* x = wb + (size_t)fr * FS;
                y256 = (x[256] - PRE * x[255]) * win[256];
            }
            float s8[8] = {y256, 0.f, 0.f, 0.f, 0.f, 0.f, 0.f, 0.f};
            u32 byte = (u32)rr * 320u + ((((u32)(16 + grp)) * 16u) ^ ((((u32)rr >> 1) & 3u) << 4));
            pack_write(s8, T + C1_SH, T + C1_SL, byte);
        }
    }
    __syncthreads();

    // ---- GEMM chunk1: Re ks 4..8 (5 ks, A=s RS320 SWT1), Im ks 4..7 (A=d RS272) ----
    dft_pass<320, 1, 5, RE_KS>(T + C1_SH, T + C1_SL, wsb + OFF_REH, wsb + OFF_REL, 4, g, lane, accR);
    dft_pass<272, 2, 4, IM_KS>(T + C1_DH, T + C1_DL, wsb + OFF_IMH, wsb + OFF_IML, 4, g, lane, accI);
    __syncthreads();

    // ---- power with mean correction -> LDS bf16 [32][256] (512-B stride) ----
    {
        const float* cs = (const float*)(wsb + OFF_CS);
        #pragma unroll
        for (int mf = 0; mf < 2; ++mf)
            #pragma unroll
            for (int j = 0; j < 4; ++j) {
                const u32 bin = (u32)(64 * g + j * 16 + cg);
                const float Cb = cs[bin], Sb = cs[256 + bin];
                #pragma unroll
                for (int r = 0; r < 4; ++r) {
                    u32 row = (u32)(mf * 16 + (q << 2) + r);
                    const float mcr = (1.0f - PRE) * smean[row];
                    float pR = accR[mf][j][r] - mcr * Cb;
                    float pI = accI[mf][j][r] - mcr * Sb;
                    float pw = pR * pR + pI * pI;
                    u32 byte = (row * 512u + bin * 2u) ^ ((row & 7u) << 4);
                    *(u16*)(T + byte) = f2bf(pw);
                }
            }
    }
    __syncthreads();

    // ---- mel GEMM (M=32, N=96 padded, K=256) + log epilogue ----
    const u16* melb = wsb + OFF_MEL;
    {
        const int mfm = w >> 1;            // rows mfm*16..+15
        const int nf0 = (w & 1) ? 3 : 0;   // frag trio {0,1,2} or {3,4,5(pad)}
        f32x4 accM[3];
        #pragma unroll
        for (int j = 0; j < 3; ++j) accM[j] = (f32x4)0.f;
        for (int ks = 0; ks < 8; ++ks) {
            u32 row = (u32)(mfm * 16 + cg);
            u32 byte = (row * 512u + (u32)(ks * 32 + (q << 3)) * 2u) ^ ((row & 7u) << 4);
            bf16x8 aP = *(const bf16x8*)(T + byte);
            #pragma unroll
            for (int j = 0; j < 3; ++j) {
                bf16x8 bM = *(const bf16x8*)(melb + ((size_t)((nf0 + j) * 8 + ks) * 64 + lane) * 8);
                accM[j] = __builtin_amdgcn_mfma_f32_16x16x32_bf16(aP, bM, accM[j], 0, 0, 0);
            }
        }
        #pragma unroll
        for (int j = 0; j < 3; ++j) {
            const int m = (nf0 + j) * 16 + cg;
            #pragma unroll
            for (int r = 0; r < 4; ++r) {
                const int rowl = mfm * 16 + (q << 2) + r;
                const int fr = f0 + rowl;
                if (fr < NFRAMES && m < NM) {
                    float v = fmaxf(accM[j][r] + EPSF, EPSF);
                    out[((size_t)b * NFRAMES + fr) * NM + m] = logf(v);
                }
            }
        }
    }
}

// ---------------- fallback (fp32 kernel, used if ws too small) ----------------
#define TFB 16
#define NB 256
__global__ __launch_bounds__(256, 3) void fbank_fallback(
    const float* __restrict__ wave, const float* __restrict__ win,
    const float* __restrict__ dftr, const float* __restrict__ dfti,
    const float* __restrict__ melw, float* __restrict__ out) {
    __shared__ float s_fr[TFB][PW];
    __shared__ float s_pw[TFB][NB + 1];
    const int tid = threadIdx.x, wv = tid >> 6, lane = tid & 63;
    const int fbase = blockIdx.x * TFB;
    #pragma unroll
    for (int j = 0; j < TFB / 4; ++j) {
        const int lf = wv * (TFB / 4) + j;
        const int gid = fbase + lf;
        const int bb = gid / NFRAMES;
        const int fr = gid - bb * NFRAMES;
        const float* x = wave + (size_t)bb * TLEN + (size_t)fr * FS;
        float s = 0.f;
        for (int i = lane; i < FL; i += 64) s += x[i];
        #pragma unroll
        for (int off = 32; off >= 1; off >>= 1) s += __shfl_xor(s, off);
        const float mean = s * (1.0f / FL);
        for (int i = lane; i < FL; i += 64) {
            const float xi = x[i];
            const float xm = (i == 0) ? xi : x[i - 1];
            s_fr[lf][i] = (xi - PRE * xm - (1.0f - PRE) * mean) * win[i];
        }
        for (int i = FL + lane; i < PW; i += 64) s_fr[lf][i] = 0.f;
    }
    __syncthreads();
    {
        const int bin = tid;
        const float4* dr4 = (const float4*)(dftr + (size_t)bin * PW);
        const float4* di4 = (const float4*)(dfti + (size_t)bin * PW);
        float accr[TFB], acci[TFB];
        #pragma unroll
        for (int f = 0; f < TFB; ++f) { accr[f] = 0.f; acci[f] = 0.f; }
        for (int k4 = 0; k4 < PW / 4; ++k4) {
            const float4 r = dr4[k4], im = di4[k4];
            #pragma unroll
            for (int f = 0; f < TFB; ++f) {
                const float4 fr = *(const float4*)&s_fr[f][k4 * 4];
                accr[f] += fr.x * r.x + fr.y * r.y + fr.z * r.z + fr.w * r.w;
                acci[f] += fr.x * im.x + fr.y * im.y + fr.z * im.z + fr.w * im.w;
            }
        }
        #pragma unroll
        for (int f = 0; f < TFB; ++f) s_pw[f][bin] = accr[f] * accr[f] + acci[f] * acci[f];
    }
    __syncthreads();
    for (int o = tid; o < TFB * NM; o += 256) {
        const int f = o / NM, m = o - f * NM;
        const float* wm = melw + (size_t)m * 257;
        float acc = 0.f;
        for (int k = 0; k < NB; ++k) acc += s_pw[f][k] * wm[k];
        out[(size_t)(fbase + f) * NM + m] = logf(fmaxf(acc + EPSF, EPSF));
    }
}

extern "C" void kernel_launch(void* const* d_in, const int* in_sizes, int n_in,
                              void* d_out, int out_size, void* d_ws, size_t ws_size,
                              hipStream_t stream) {
    const float* wave = (const float*)d_in[0];
    const float* win  = (const float*)d_in[1];
    const float* dftr = (const float*)d_in[2];
    const float* dfti = (const float*)d_in[3];
    const float* melw = (const float*)d_in[4];
    float* out = (float*)d_out;

    if (ws_size >= WS_NEED) {
        u16* wsb = (u16*)d_ws;
        const int prep_threads = 16 * RE_KS * 64 + 16 * IM_KS * 64 + 6 * 8 * 64 + 512;  // 20992
        prep_kernel<<<(prep_threads + 255) / 256, 256, 0, stream>>>(dftr, dfti, melw, win, wsb);
        dim3 grid(NTILES, BATCH);
        fbank_mfma<<<grid, 256, 0, stream>>>(wave, win, wsb, out);
    } else {
        const int nblocks = (BATCH * NFRAMES) / TFB;
        fbank_fallback<<<nblocks, 256, 0, stream>>>(wave, win, dftr, dfti, melw, out);
    }
}

// Round 14
// 128.719 us; speedup vs baseline: 1.1975x; 1.1975x over previous
//
#include <hip/hip_runtime.h>
#include <math.h>

// Fbank via split-bf16 MFMA + real-DFT folding. R14 = R13 with the C/S
// rank-1-correction table computed by a wave-per-bin kernel (R13 used 512
// serial threads -> ~30us latency chain in the captured graph = the whole
// R13 bench regression). Main kernel unchanged from R13.

#define BATCH 32
#define TLEN 480000
#define NFRAMES 2998
#define FL 400
#define FS 160
#define PW 512
#define NM 80
#define MT 32                // frames per block
#define NTILES 94            // ceil(2998/32)
#define PRE 0.97f
#define EPSF 1e-6f

#define RE_KS 9              // K=288 (t 0..256 + pad)
#define IM_KS 8              // K=256 (t 0..255)
#define RE_U16 (16 * RE_KS * 64 * 8)   // 73728
#define IM_U16 (16 * IM_KS * 64 * 8)   // 65536
#define MEL_U16 (6 * 8 * 64 * 8)       // 24576
#define OFF_REH 0
#define OFF_REL RE_U16
#define OFF_IMH (2 * RE_U16)
#define OFF_IML (2 * RE_U16 + IM_U16)
#define OFF_MEL (2 * RE_U16 + 2 * IM_U16)
#define OFF_CS  (OFF_MEL + MEL_U16)          // u16 units; 512 floats follow
#define WS_NEED ((size_t)OFF_CS * 2 + 512 * 4)   // ~608 KB

// LDS tile byte offsets. 128-col tiles: 272-B row stride (natural bank
// rotation, no XOR). 160-col chunk1 s-tile: 320-B stride + SWT1 XOR.
#define C0_SH 0
#define C0_SL 8704
#define C0_DH 17408
#define C0_DL 26112          // chunk0 total 34,816 B
#define C1_SH 0
#define C1_SL 10240
#define C1_DH 20480
#define C1_DL 29184          // chunk1 total 37,888 B

typedef short bf16x8 __attribute__((ext_vector_type(8)));
typedef float f32x4 __attribute__((ext_vector_type(4)));
typedef unsigned int u32;
typedef unsigned short u16;
typedef u32 u32x4 __attribute__((ext_vector_type(4)));

__device__ __forceinline__ u16 f2bf(float f) {
    u32 u = __builtin_bit_cast(u32, f);
    return (u16)((u + 0x7FFFu + ((u >> 16) & 1u)) >> 16);
}
__device__ __forceinline__ float bf2f(u16 h) {
    u32 u = ((u32)h) << 16;
    return __builtin_bit_cast(float, u);
}

// ---------------- prep: folded B (cos/sin hi+lo) + mel ----------------
__global__ void prep_kernel(const float* __restrict__ dftr, const float* __restrict__ dfti,
                            const float* __restrict__ melw, u16* __restrict__ wsb) {
    int idx = blockIdx.x * 256 + threadIdx.x;
    if (idx < 16 * RE_KS * 64) {                       // 9216 Re groups
        int nf = idx / (RE_KS * 64);
        int rem = idx - nf * (RE_KS * 64);
        int ks = rem >> 6, l = rem & 63;
        int f = nf * 16 + (l & 15);
        int k = ks * 32 + ((l >> 4) << 3);
        u16* dh = wsb + OFF_REH + (size_t)idx * 8;
        u16* dl = wsb + OFF_REL + (size_t)idx * 8;
        #pragma unroll
        for (int e = 0; e < 8; ++e) {
            int kk = k + e;
            float x = (kk <= 256) ? dftr[(size_t)f * PW + kk] : 0.f;
            u16 h = f2bf(x);
            dh[e] = h;
            dl[e] = f2bf(x - bf2f(h));
        }
    } else if (idx < 16 * RE_KS * 64 + 16 * IM_KS * 64) {   // 8192 Im groups
        int j = idx - 16 * RE_KS * 64;
        int nf = j / (IM_KS * 64);
        int rem = j - nf * (IM_KS * 64);
        int ks = rem >> 6, l = rem & 63;
        int f = nf * 16 + (l & 15);
        int k = ks * 32 + ((l >> 4) << 3);
        u16* dh = wsb + OFF_IMH + (size_t)j * 8;
        u16* dl = wsb + OFF_IML + (size_t)j * 8;
        #pragma unroll
        for (int e = 0; e < 8; ++e) {
            float x = dfti[(size_t)f * PW + k + e];    // k+e <= 255
            u16 h = f2bf(x);
            dh[e] = h;
            dl[e] = f2bf(x - bf2f(h));
        }
    } else {                                            // mel groups
        int m = idx - (16 * RE_KS * 64 + 16 * IM_KS * 64);
        if (m < 6 * 8 * 64) {
            int nf = m / (8 * 64);
            int ks = (m >> 6) & 7, l = m & 63;
            int n = nf * 16 + (l & 15);
            int k = ks * 32 + ((l >> 4) << 3);
            u16* dst = wsb + OFF_MEL + (size_t)m * 8;
            #pragma unroll
            for (int e = 0; e < 8; ++e)
                dst[e] = (n < NM) ? f2bf(melw[(size_t)n * 257 + k + e]) : (u16)0;
        }
    }
}

// ---------------- prep C/S: one wave per bin (512 waves) ----------------
__global__ void prep_cs_kernel(const float* __restrict__ dftr, const float* __restrict__ dfti,
                               const float* __restrict__ win, u16* __restrict__ wsb) {
    const int gw = (blockIdx.x * 256 + threadIdx.x) >> 6;   // 0..511
    const int lane = threadIdx.x & 63;
    float* cs = (float*)(wsb + OFF_CS);
    float acc = 0.f;
    if (gw < 256) {
        const int f = gw;
        for (int t = lane; t <= 256; t += 64) {
            float wt = (t < FL) ? win[t] : 0.f;
            float wu = (t >= 1 && t < 256 && (512 - t) < FL) ? win[512 - t] : 0.f;
            acc += (wt + wu) * dftr[(size_t)f * PW + t];
        }
    } else {
        const int ff = gw - 256;
        for (int t = lane; t <= 255; t += 64) {
            float wt = (t < FL) ? win[t] : 0.f;
            float wu = (t >= 1 && (512 - t) < FL) ? win[512 - t] : 0.f;
            acc += (wt - wu) * dfti[(size_t)ff * PW + t];
        }
    }
    #pragma unroll
    for (int o = 32; o; o >>= 1) acc += __shfl_xor(acc, o);
    if (lane == 0) cs[gw] = acc;
}

// swizzle select: 0 -> (r&7)<<4 (512-B stride), 1 -> ((r>>1)&3)<<4 (320-B), 2 -> none (272-B)
__device__ __forceinline__ u32 swz(int SWT, u32 r) {
    return (SWT == 0) ? ((r & 7u) << 4) : (SWT == 1) ? (((r >> 1) & 3u) << 4) : 0u;
}

// 6 MFMA for one (bh,bl) ping-pong slot: 2 m-frags x 3 split-product terms
#define MFMA6(D, J)                                                                        \
    _Pragma("unroll")                                                                      \
    for (int mf = 0; mf < 2; ++mf) {                                                       \
        acc[mf][J] = __builtin_amdgcn_mfma_f32_16x16x32_bf16(aH[mf], D[0], acc[mf][J], 0, 0, 0); \
        acc[mf][J] = __builtin_amdgcn_mfma_f32_16x16x32_bf16(aL[mf], D[0], acc[mf][J], 0, 0, 0); \
        acc[mf][J] = __builtin_amdgcn_mfma_f32_16x16x32_bf16(aH[mf], D[1], acc[mf][J], 0, 0, 0); \
    }

// ---------------- DFT pass: split product, B ping-pong prefetch ----------------
template<int RS, int SWT, int NKS, int BKS>
__device__ __forceinline__ void dft_pass(
    const char* tH, const char* tL,
    const u16* __restrict__ bH, const u16* __restrict__ bL,
    int ks0, int g, int lane, f32x4 (&acc)[2][4]) {

    bf16x8 aH[2], aL[2], Ba[2], Bb[2];

#define LDA_P(KS)                                                              \
    { _Pragma("unroll")                                                        \
      for (int mf = 0; mf < 2; ++mf) {                                         \
        u32 r = (u32)(mf * 16 + (lane & 15));                                  \
        u32 off = (u32)((KS) * 64 + ((lane >> 4) << 4));                       \
        u32 byte = r * RS + (off ^ swz(SWT, r));                               \
        aH[mf] = *(const bf16x8*)(tH + byte);                                  \
        aL[mf] = *(const bf16x8*)(tL + byte);                                  \
      } }
#define LDB_P(KSG, J, D)                                                       \
    {                                                                          \
        size_t o = ((size_t)((4 * g + (J)) * BKS + (KSG)) * 64 + lane) * 8;    \
        D[0] = *(const bf16x8*)(bH + o);                                       \
        D[1] = *(const bf16x8*)(bL + o);                                       \
    }

    LDB_P(ks0, 0, Ba);
    #pragma unroll
    for (int ks = 0; ks < NKS; ++ks) {
        LDA_P(ks);
        LDB_P(ks0 + ks, 1, Bb);
        MFMA6(Ba, 0);
        LDB_P(ks0 + ks, 2, Ba);
        MFMA6(Bb, 1);
        LDB_P(ks0 + ks, 3, Bb);
        MFMA6(Ba, 2);
        if (ks + 1 < NKS) LDB_P(ks0 + ks + 1, 0, Ba);
        MFMA6(Bb, 3);
    }
#undef LDA_P
#undef LDB_P
}

__device__ __forceinline__ void pack_write(const float* ys, char* baseH, char* baseL, u32 byte) {
    u32x4 hv, lv;
    #pragma unroll
    for (int e = 0; e < 4; ++e) {
        u16 h0 = f2bf(ys[2 * e]), h1 = f2bf(ys[2 * e + 1]);
        hv[e] = (u32)h0 | ((u32)h1 << 16);
        u16 l0 = f2bf(ys[2 * e] - bf2f(h0)), l1 = f2bf(ys[2 * e + 1] - bf2f(h1));
        lv[e] = (u32)l0 | ((u32)l1 << 16);
    }
    *(u32x4*)(baseH + byte) = hv;
    *(u32x4*)(baseL + byte) = lv;
}

// ---------------- main fused kernel (unchanged from R13) ----------------
__global__ __launch_bounds__(256, 3) void fbank_mfma(
    const float* __restrict__ wave, const float* __restrict__ win,
    const u16* __restrict__ wsb, float* __restrict__ out) {
    __shared__ float smean[MT];
    __shared__ u16 stile[18944];       // 37,888 B tile buffer (power overlay fits)
    char* T = (char*)stile;

    const int tid = threadIdx.x, w = tid >> 6, lane = tid & 63;
    const int q = lane >> 4;           // frame sub-row within step
    const int cg = lane & 15;          // col-group
    const int b = blockIdx.y;
    const int f0 = blockIdx.x * MT;
    const float* wb = wave + (size_t)b * TLEN;
    const float4* win4 = (const float4*)win;

    float ps[2] = {0.f, 0.f};          // per-frame waveform partial sums (for mean)

    // ---- P1b: chunk0 (t 0..127): build x-only s,d tiles (272-B stride, no XOR) ----
    #pragma unroll
    for (int i = 0; i < 2; ++i) {
        const int rr = w * 8 + i * 4 + q;
        const int fr = f0 + rr;
        const bool valid = fr < NFRAMES;
        const float* x = wb + (size_t)fr * FS;
        const float4* x4 = (const float4*)x;

        float4 v0 = {0,0,0,0}, v1 = {0,0,0,0};
        if (valid) { v0 = x4[2 * cg]; v1 = x4[2 * cg + 1]; }
        ps[i] += v0.x + v0.y + v0.z + v0.w + v1.x + v1.y + v1.z + v1.w;
        float4 w0 = win4[2 * cg], w1 = win4[2 * cg + 1];
        float xpn = __shfl(v1.w, lane - 1);
        float xprev = (cg == 0) ? v0.x : xpn;
        float y[8];
        y[0] = (v0.x - PRE * xprev) * w0.x;
        y[1] = (v0.y - PRE * v0.x) * w0.y;
        y[2] = (v0.z - PRE * v0.y) * w0.z;
        y[3] = (v0.w - PRE * v0.z) * w0.w;
        y[4] = (v1.x - PRE * v0.w) * w1.x;
        y[5] = (v1.y - PRE * v1.x) * w1.y;
        y[6] = (v1.z - PRE * v1.y) * w1.z;
        y[7] = (v1.w - PRE * v1.z) * w1.w;

        float yr[8];
        #pragma unroll
        for (int e = 0; e < 8; ++e) yr[e] = 0.f;
        if (cg >= 14) {                      // t >= 113 folds (u = 512-t in 385..399)
            const int u0 = 512 - 8 * cg;     // 400 (cg14) or 392 (cg15)
            float4 xr0 = {0,0,0,0}, xr1 = {0,0,0,0};
            float xu0 = 0.f;
            if (valid) {
                xr0 = x4[u0 / 4 - 2]; xr1 = x4[u0 / 4 - 1];
                if (u0 <= 399) xu0 = x[u0];
            }
            ps[i] += xr0.x + xr0.y + xr0.z + xr0.w + xr1.x + xr1.y + xr1.z + xr1.w;
            float4 wr0 = win4[u0 / 4 - 2], wr1 = win4[u0 / 4 - 1];
            float wu0 = (u0 <= 399) ? win[u0] : 0.f;
            yr[0] = (xu0   - PRE * xr1.w) * wu0;
            yr[1] = (xr1.w - PRE * xr1.z) * wr1.w;
            yr[2] = (xr1.z - PRE * xr1.y) * wr1.z;
            yr[3] = (xr1.y - PRE * xr1.x) * wr1.y;
            yr[4] = (xr1.x - PRE * xr0.w) * wr1.x;
            yr[5] = (xr0.w - PRE * xr0.z) * wr0.w;
            yr[6] = (xr0.z - PRE * xr0.y) * wr0.z;
            yr[7] = (xr0.y - PRE * xr0.x) * wr0.y;
        }
        float s8[8], d8[8];
        #pragma unroll
        for (int e = 0; e < 8; ++e) { s8[e] = y[e] + yr[e]; d8[e] = y[e] - yr[e]; }
        u32 byte = (u32)rr * 272u + (u32)cg * 16u;
        pack_write(s8, T + C0_SH, T + C0_SL, byte);
        pack_write(d8, T + C0_DH, T + C0_DL, byte);
    }
    __syncthreads();

    // ---- GEMM chunk0: Re ks 0..3 (A=s), Im ks 0..3 (A=d) ----
    const int g = w;
    f32x4 accR[2][4], accI[2][4];
    #pragma unroll
    for (int mf = 0; mf < 2; ++mf)
        #pragma unroll
        for (int j = 0; j < 4; ++j) { accR[mf][j] = (f32x4)0.f; accI[mf][j] = (f32x4)0.f; }

    dft_pass<272, 2, 4, RE_KS>(T + C0_SH, T + C0_SL, wsb + OFF_REH, wsb + OFF_REL, 0, g, lane, accR);
    dft_pass<272, 2, 4, IM_KS>(T + C0_DH, T + C0_DL, wsb + OFF_IMH, wsb + OFF_IML, 0, g, lane, accI);
    __syncthreads();

    // ---- P1c: chunk1 (t 128..255 fold; s also t 256..287 tail) ----
    #pragma unroll
    for (int i = 0; i < 2; ++i) {
        const int rr = w * 8 + i * 4 + q;
        const int fr = f0 + rr;
        const bool valid = fr < NFRAMES;
        const float* x = wb + (size_t)fr * FS;
        const float4* x4 = (const float4*)x;

        float4 v0 = {0,0,0,0}, v1 = {0,0,0,0};
        if (valid) { v0 = x4[32 + 2 * cg]; v1 = x4[33 + 2 * cg]; }
        ps[i] += v0.x + v0.y + v0.z + v0.w + v1.x + v1.y + v1.z + v1.w;
        float4 w0 = win4[32 + 2 * cg], w1 = win4[33 + 2 * cg];
        float xpn = __shfl(v1.w, lane - 1);
        float xprev = (cg == 0) ? (valid ? x[127] : 0.f) : xpn;
        float y[8];
        y[0] = (v0.x - PRE * xprev) * w0.x;
        y[1] = (v0.y - PRE * v0.x) * w0.y;
        y[2] = (v0.z - PRE * v0.y) * w0.z;
        y[3] = (v0.w - PRE * v0.z) * w0.w;
        y[4] = (v1.x - PRE * v0.w) * w1.x;
        y[5] = (v1.y - PRE * v1.x) * w1.y;
        y[6] = (v1.z - PRE * v1.y) * w1.z;
        y[7] = (v1.w - PRE * v1.z) * w1.w;

        const int u0 = 384 - 8 * cg;        // 264..384, all fold
        float4 xr0 = {0,0,0,0}, xr1 = {0,0,0,0};
        float xu0 = 0.f;
        if (valid) { xr0 = x4[u0 / 4 - 2]; xr1 = x4[u0 / 4 - 1]; xu0 = x[u0]; }
        ps[i] += xr0.x + xr0.y + xr0.z + xr0.w + xr1.x + xr1.y + xr1.z + xr1.w;
        float4 wr0 = win4[u0 / 4 - 2], wr1 = win4[u0 / 4 - 1];
        float wu0 = win[u0];
        float yr[8];
        yr[0] = (xu0   - PRE * xr1.w) * wu0;
        yr[1] = (xr1.w - PRE * xr1.z) * wr1.w;
        yr[2] = (xr1.z - PRE * xr1.y) * wr1.z;
        yr[3] = (xr1.y - PRE * xr1.x) * wr1.y;
        yr[4] = (xr1.x - PRE * xr0.w) * wr1.x;
        yr[5] = (xr0.w - PRE * xr0.z) * wr0.w;
        yr[6] = (xr0.z - PRE * xr0.y) * wr0.z;
        yr[7] = (xr0.y - PRE * xr0.x) * wr0.y;

        float s8[8], d8[8];
        #pragma unroll
        for (int e = 0; e < 8; ++e) { s8[e] = y[e] + yr[e]; d8[e] = y[e] - yr[e]; }
        u32 byteS = (u32)rr * 320u + (((u32)cg * 16u) ^ ((((u32)rr >> 1) & 3u) << 4));
        u32 byteD = (u32)rr * 272u + (u32)cg * 16u;
        pack_write(s8, T + C1_SH, T + C1_SL, byteS);
        pack_write(d8, T + C1_DH, T + C1_DL, byteD);

        // finalize mean for this frame (samples 0..399 covered exactly once)
        float acc = ps[i];
        #pragma unroll
        for (int o = 8; o; o >>= 1) acc += __shfl_xor(acc, o);
        if (cg == 0) smean[rr] = acc * (1.0f / FL);
    }
    // s tail: cols t=256..287 (units 16..19): only t=256 nonzero (x-only)
    {
        const int rr = tid & 31;
        const int grp = tid >> 5;          // 0..7; units 16..19 served by grp<4
        if (grp < 4) {
            const int fr = f0 + rr;
            float y256 = 0.f;
            if (grp == 0 && fr < NFRAMES) {
                const float* x = wb + (size_t)fr * FS;
                y256 = (x[256] - PRE * x[255]) * win[256];
            }
            float s8[8] = {y256, 0.f, 0.f, 0.f, 0.f, 0.f, 0.f, 0.f};
            u32 byte = (u32)rr * 320u + ((((u32)(16 + grp)) * 16u) ^ ((((u32)rr >> 1) & 3u) << 4));
            pack_write(s8, T + C1_SH, T + C1_SL, byte);
        }
    }
    __syncthreads();

    // ---- GEMM chunk1: Re ks 4..8 (5 ks, A=s RS320 SWT1), Im ks 4..7 (A=d RS272) ----
    dft_pass<320, 1, 5, RE_KS>(T + C1_SH, T + C1_SL, wsb + OFF_REH, wsb + OFF_REL, 4, g, lane, accR);
    dft_pass<272, 2, 4, IM_KS>(T + C1_DH, T + C1_DL, wsb + OFF_IMH, wsb + OFF_IML, 4, g, lane, accI);
    __syncthreads();

    // ---- power with mean correction -> LDS bf16 [32][256] (512-B stride) ----
    {
        const float* cs = (const float*)(wsb + OFF_CS);
        #pragma unroll
        for (int mf = 0; mf < 2; ++mf)
            #pragma unroll
            for (int j = 0; j < 4; ++j) {
                const u32 bin = (u32)(64 * g + j * 16 + cg);
                const float Cb = cs[bin], Sb = cs[256 + bin];
                #pragma unroll
                for (int r = 0; r < 4; ++r) {
                    u32 row = (u32)(mf * 16 + (q << 2) + r);
                    const float mcr = (1.0f - PRE) * smean[row];
                    float pR = accR[mf][j][r] - mcr * Cb;
                    float pI = accI[mf][j][r] - mcr * Sb;
                    float pw = pR * pR + pI * pI;
                    u32 byte = (row * 512u + bin * 2u) ^ ((row & 7u) << 4);
                    *(u16*)(T + byte) = f2bf(pw);
                }
            }
    }
    __syncthreads();

    // ---- mel GEMM (M=32, N=96 padded, K=256) + log epilogue ----
    const u16* melb = wsb + OFF_MEL;
    {
        const int mfm = w >> 1;            // rows mfm*16..+15
        const int nf0 = (w & 1) ? 3 : 0;   // frag trio {0,1,2} or {3,4,5(pad)}
        f32x4 accM[3];
        #pragma unroll
        for (int j = 0; j < 3; ++j) accM[j] = (f32x4)0.f;
        for (int ks = 0; ks < 8; ++ks) {
            u32 row = (u32)(mfm * 16 + cg);
            u32 byte = (row * 512u + (u32)(ks * 32 + (q << 3)) * 2u) ^ ((row & 7u) << 4);
            bf16x8 aP = *(const bf16x8*)(T + byte);
            #pragma unroll
            for (int j = 0; j < 3; ++j) {
                bf16x8 bM = *(const bf16x8*)(melb + ((size_t)((nf0 + j) * 8 + ks) * 64 + lane) * 8);
                accM[j] = __builtin_amdgcn_mfma_f32_16x16x32_bf16(aP, bM, accM[j], 0, 0, 0);
            }
        }
        #pragma unroll
        for (int j = 0; j < 3; ++j) {
            const int m = (nf0 + j) * 16 + cg;
            #pragma unroll
            for (int r = 0; r < 4; ++r) {
                const int rowl = mfm * 16 + (q << 2) + r;
                const int fr = f0 + rowl;
                if (fr < NFRAMES && m < NM) {
                    float v = fmaxf(accM[j][r] + EPSF, EPSF);
                    out[((size_t)b * NFRAMES + fr) * NM + m] = logf(v);
                }
            }
        }
    }
}

// ---------------- fallback (fp32 kernel, used if ws too small) ----------------
#define TFB 16
#define NB 256
__global__ __launch_bounds__(256, 3) void fbank_fallback(
    const float* __restrict__ wave, const float* __restrict__ win,
    const float* __restrict__ dftr, const float* __restrict__ dfti,
    const float* __restrict__ melw, float* __restrict__ out) {
    __shared__ float s_fr[TFB][PW];
    __shared__ float s_pw[TFB][NB + 1];
    const int tid = threadIdx.x, wv = tid >> 6, lane = tid & 63;
    const int fbase = blockIdx.x * TFB;
    #pragma unroll
    for (int j = 0; j < TFB / 4; ++j) {
        const int lf = wv * (TFB / 4) + j;
        const int gid = fbase + lf;
        const int bb = gid / NFRAMES;
        const int fr = gid - bb * NFRAMES;
        const float* x = wave + (size_t)bb * TLEN + (size_t)fr * FS;
        float s = 0.f;
        for (int i = lane; i < FL; i += 64) s += x[i];
        #pragma unroll
        for (int off = 32; off >= 1; off >>= 1) s += __shfl_xor(s, off);
        const float mean = s * (1.0f / FL);
        for (int i = lane; i < FL; i += 64) {
            const float xi = x[i];
            const float xm = (i == 0) ? xi : x[i - 1];
            s_fr[lf][i] = (xi - PRE * xm - (1.0f - PRE) * mean) * win[i];
        }
        for (int i = FL + lane; i < PW; i += 64) s_fr[lf][i] = 0.f;
    }
    __syncthreads();
    {
        const int bin = tid;
        const float4* dr4 = (const float4*)(dftr + (size_t)bin * PW);
        const float4* di4 = (const float4*)(dfti + (size_t)bin * PW);
        float accr[TFB], acci[TFB];
        #pragma unroll
        for (int f = 0; f < TFB; ++f) { accr[f] = 0.f; acci[f] = 0.f; }
        for (int k4 = 0; k4 < PW / 4; ++k4) {
            const float4 r = dr4[k4], im = di4[k4];
            #pragma unroll
            for (int f = 0; f < TFB; ++f) {
                const float4 fr = *(const float4*)&s_fr[f][k4 * 4];
                accr[f] += fr.x * r.x + fr.y * r.y + fr.z * r.z + fr.w * r.w;
                acci[f] += fr.x * im.x + fr.y * im.y + fr.z * im.z + fr.w * im.w;
            }
        }
        #pragma unroll
        for (int f = 0; f < TFB; ++f) s_pw[f][bin] = accr[f] * accr[f] + acci[f] * acci[f];
    }
    __syncthreads();
    for (int o = tid; o < TFB * NM; o += 256) {
        const int f = o / NM, m = o - f * NM;
        const float* wm = melw + (size_t)m * 257;
        float acc = 0.f;
        for (int k = 0; k < NB; ++k) acc += s_pw[f][k] * wm[k];
        out[(size_t)(fbase + f) * NM + m] = logf(fmaxf(acc + EPSF, EPSF));
    }
}

extern "C" void kernel_launch(void* const* d_in, const int* in_sizes, int n_in,
                              void* d_out, int out_size, void* d_ws, size_t ws_size,
                              hipStream_t stream) {
    const float* wave = (const float*)d_in[0];
    const float* win  = (const float*)d_in[1];
    const float* dftr = (const float*)d_in[2];
    const float* dfti = (const float*)d_in[3];
    const float* melw = (const float*)d_in[4];
    float* out = (float*)d_out;

    if (ws_size >= WS_NEED) {
        u16* wsb = (u16*)d_ws;
        const int prep_threads = 16 * RE_KS * 64 + 16 * IM_KS * 64 + 6 * 8 * 64;  // 20480
        prep_kernel<<<(prep_threads + 255) / 256, 256, 0, stream>>>(dftr, dfti, melw, wsb);
        prep_cs_kernel<<<128, 256, 0, stream>>>(dftr, dfti, win, wsb);   // 512 waves, 1/bin
        dim3 grid(NTILES, BATCH);
        fbank_mfma<<<grid, 256, 0, stream>>>(wave, win, wsb, out);
    } else {
        const int nblocks = (BATCH * NFRAMES) / TFB;
        fbank_fallback<<<nblocks, 256, 0, stream>>>(wave, win, dftr, dfti, melw, out);
    }
}

// Round 15
// 119.114 us; speedup vs baseline: 1.2940x; 1.0806x over previous
//
#include <hip/hip_runtime.h>
#include <math.h>

// Fbank via split-bf16 MFMA + real-DFT folding. R15: 512-thread / 8-wave
// blocks (same MT=32 tile). Per-wave state halves (32 AGPR acc, 2 n-frags,
// 4 pack-frames) -> ~117 regs -> __launch_bounds__(512,4) = 4 waves/SIMD
// = 16 waves/CU (50% occ) vs R14's 12 (37.5%). Latency-bound kernel: TLP up.

#define BATCH 32
#define TLEN 480000
#define NFRAMES 2998
#define FL 400
#define FS 160
#define PW 512
#define NM 80
#define MT 32                // frames per block
#define NTILES 94            // ceil(2998/32)
#define PRE 0.97f
#define EPSF 1e-6f

#define RE_KS 9              // K=288 (t 0..256 + pad)
#define IM_KS 8              // K=256 (t 0..255)
#define RE_U16 (16 * RE_KS * 64 * 8)   // 73728
#define IM_U16 (16 * IM_KS * 64 * 8)   // 65536
#define MEL_U16 (6 * 8 * 64 * 8)       // 24576
#define OFF_REH 0
#define OFF_REL RE_U16
#define OFF_IMH (2 * RE_U16)
#define OFF_IML (2 * RE_U16 + IM_U16)
#define OFF_MEL (2 * RE_U16 + 2 * IM_U16)
#define OFF_CS  (OFF_MEL + MEL_U16)          // u16 units; 512 floats follow
#define WS_NEED ((size_t)OFF_CS * 2 + 512 * 4)   // ~608 KB

// LDS tile byte offsets. 128-col tiles: 272-B row stride (natural bank
// rotation, no XOR). 160-col chunk1 s-tile: 320-B stride + SWT1 XOR.
#define C0_SH 0
#define C0_SL 8704
#define C0_DH 17408
#define C0_DL 26112          // chunk0 total 34,816 B
#define C1_SH 0
#define C1_SL 10240
#define C1_DH 20480
#define C1_DL 29184          // chunk1 total 37,888 B

typedef short bf16x8 __attribute__((ext_vector_type(8)));
typedef float f32x4 __attribute__((ext_vector_type(4)));
typedef unsigned int u32;
typedef unsigned short u16;
typedef u32 u32x4 __attribute__((ext_vector_type(4)));

__device__ __forceinline__ u16 f2bf(float f) {
    u32 u = __builtin_bit_cast(u32, f);
    return (u16)((u + 0x7FFFu + ((u >> 16) & 1u)) >> 16);
}
__device__ __forceinline__ float bf2f(u16 h) {
    u32 u = ((u32)h) << 16;
    return __builtin_bit_cast(float, u);
}

// ---------------- prep: folded B (cos/sin hi+lo) + mel ----------------
__global__ void prep_kernel(const float* __restrict__ dftr, const float* __restrict__ dfti,
                            const float* __restrict__ melw, u16* __restrict__ wsb) {
    int idx = blockIdx.x * 256 + threadIdx.x;
    if (idx < 16 * RE_KS * 64) {                       // 9216 Re groups
        int nf = idx / (RE_KS * 64);
        int rem = idx - nf * (RE_KS * 64);
        int ks = rem >> 6, l = rem & 63;
        int f = nf * 16 + (l & 15);
        int k = ks * 32 + ((l >> 4) << 3);
        u16* dh = wsb + OFF_REH + (size_t)idx * 8;
        u16* dl = wsb + OFF_REL + (size_t)idx * 8;
        #pragma unroll
        for (int e = 0; e < 8; ++e) {
            int kk = k + e;
            float x = (kk <= 256) ? dftr[(size_t)f * PW + kk] : 0.f;
            u16 h = f2bf(x);
            dh[e] = h;
            dl[e] = f2bf(x - bf2f(h));
        }
    } else if (idx < 16 * RE_KS * 64 + 16 * IM_KS * 64) {   // 8192 Im groups
        int j = idx - 16 * RE_KS * 64;
        int nf = j / (IM_KS * 64);
        int rem = j - nf * (IM_KS * 64);
        int ks = rem >> 6, l = rem & 63;
        int f = nf * 16 + (l & 15);
        int k = ks * 32 + ((l >> 4) << 3);
        u16* dh = wsb + OFF_IMH + (size_t)j * 8;
        u16* dl = wsb + OFF_IML + (size_t)j * 8;
        #pragma unroll
        for (int e = 0; e < 8; ++e) {
            float x = dfti[(size_t)f * PW + k + e];    // k+e <= 255
            u16 h = f2bf(x);
            dh[e] = h;
            dl[e] = f2bf(x - bf2f(h));
        }
    } else {                                            // mel groups
        int m = idx - (16 * RE_KS * 64 + 16 * IM_KS * 64);
        if (m < 6 * 8 * 64) {
            int nf = m / (8 * 64);
            int ks = (m >> 6) & 7, l = m & 63;
            int n = nf * 16 + (l & 15);
            int k = ks * 32 + ((l >> 4) << 3);
            u16* dst = wsb + OFF_MEL + (size_t)m * 8;
            #pragma unroll
            for (int e = 0; e < 8; ++e)
                dst[e] = (n < NM) ? f2bf(melw[(size_t)n * 257 + k + e]) : (u16)0;
        }
    }
}

// ---------------- prep C/S: one wave per bin (512 waves) ----------------
__global__ void prep_cs_kernel(const float* __restrict__ dftr, const float* __restrict__ dfti,
                               const float* __restrict__ win, u16* __restrict__ wsb) {
    const int gw = (blockIdx.x * 256 + threadIdx.x) >> 6;   // 0..511
    const int lane = threadIdx.x & 63;
    float* cs = (float*)(wsb + OFF_CS);
    float acc = 0.f;
    if (gw < 256) {
        const int f = gw;
        for (int t = lane; t <= 256; t += 64) {
            float wt = (t < FL) ? win[t] : 0.f;
            float wu = (t >= 1 && t < 256 && (512 - t) < FL) ? win[512 - t] : 0.f;
            acc += (wt + wu) * dftr[(size_t)f * PW + t];
        }
    } else {
        const int ff = gw - 256;
        for (int t = lane; t <= 255; t += 64) {
            float wt = (t < FL) ? win[t] : 0.f;
            float wu = (t >= 1 && (512 - t) < FL) ? win[512 - t] : 0.f;
            acc += (wt - wu) * dfti[(size_t)ff * PW + t];
        }
    }
    #pragma unroll
    for (int o = 32; o; o >>= 1) acc += __shfl_xor(acc, o);
    if (lane == 0) cs[gw] = acc;
}

// swizzle select: 0 -> (r&7)<<4 (512-B stride), 1 -> ((r>>1)&3)<<4 (320-B), 2 -> none (272-B)
__device__ __forceinline__ u32 swz(int SWT, u32 r) {
    return (SWT == 0) ? ((r & 7u) << 4) : (SWT == 1) ? (((r >> 1) & 3u) << 4) : 0u;
}

// 6 MFMA for one (bh,bl) ping-pong slot: 2 m-frags x 3 split-product terms
#define MFMA6(D, J)                                                                        \
    _Pragma("unroll")                                                                      \
    for (int mf = 0; mf < 2; ++mf) {                                                       \
        acc[mf][J] = __builtin_amdgcn_mfma_f32_16x16x32_bf16(aH[mf], D[0], acc[mf][J], 0, 0, 0); \
        acc[mf][J] = __builtin_amdgcn_mfma_f32_16x16x32_bf16(aL[mf], D[0], acc[mf][J], 0, 0, 0); \
        acc[mf][J] = __builtin_amdgcn_mfma_f32_16x16x32_bf16(aH[mf], D[1], acc[mf][J], 0, 0, 0); \
    }

// ---------------- DFT pass: 2 n-frags per wave, B ping-pong prefetch ----------------
template<int RS, int SWT, int NKS, int BKS>
__device__ __forceinline__ void dft_pass(
    const char* tH, const char* tL,
    const u16* __restrict__ bH, const u16* __restrict__ bL,
    int ks0, int w, int lane, f32x4 (&acc)[2][2]) {

    bf16x8 aH[2], aL[2], Ba[2], Bb[2];

#define LDA_P(KS)                                                              \
    { _Pragma("unroll")                                                        \
      for (int mf = 0; mf < 2; ++mf) {                                         \
        u32 r = (u32)(mf * 16 + (lane & 15));                                  \
        u32 off = (u32)((KS) * 64 + ((lane >> 4) << 4));                       \
        u32 byte = r * RS + (off ^ swz(SWT, r));                               \
        aH[mf] = *(const bf16x8*)(tH + byte);                                  \
        aL[mf] = *(const bf16x8*)(tL + byte);                                  \
      } }
#define LDB_P(KSG, J, D)                                                       \
    {                                                                          \
        size_t o = ((size_t)((2 * w + (J)) * BKS + (KSG)) * 64 + lane) * 8;    \
        D[0] = *(const bf16x8*)(bH + o);                                       \
        D[1] = *(const bf16x8*)(bL + o);                                       \
    }

    LDB_P(ks0, 0, Ba);
    #pragma unroll
    for (int ks = 0; ks < NKS; ++ks) {
        LDA_P(ks);
        LDB_P(ks0 + ks, 1, Bb);
        MFMA6(Ba, 0);
        if (ks + 1 < NKS) LDB_P(ks0 + ks + 1, 0, Ba);
        MFMA6(Bb, 1);
    }
#undef LDA_P
#undef LDB_P
}

__device__ __forceinline__ void pack_write(const float* ys, char* baseH, char* baseL, u32 byte) {
    u32x4 hv, lv;
    #pragma unroll
    for (int e = 0; e < 4; ++e) {
        u16 h0 = f2bf(ys[2 * e]), h1 = f2bf(ys[2 * e + 1]);
        hv[e] = (u32)h0 | ((u32)h1 << 16);
        u16 l0 = f2bf(ys[2 * e] - bf2f(h0)), l1 = f2bf(ys[2 * e + 1] - bf2f(h1));
        lv[e] = (u32)l0 | ((u32)l1 << 16);
    }
    *(u32x4*)(baseH + byte) = hv;
    *(u32x4*)(baseL + byte) = lv;
}

// ---------------- main fused kernel (512 threads / 8 waves) ----------------
__global__ __launch_bounds__(512, 4) void fbank_mfma(
    const float* __restrict__ wave, const float* __restrict__ win,
    const u16* __restrict__ wsb, float* __restrict__ out) {
    __shared__ float smean[MT];
    __shared__ u16 stile[18944];       // 37,888 B tile buffer (power overlay fits)
    char* T = (char*)stile;

    const int tid = threadIdx.x, w = tid >> 6, lane = tid & 63;
    const int q = lane >> 4;           // frame sub-row within wave (4 frames/wave)
    const int cg = lane & 15;          // col-group
    const int b = blockIdx.y;
    const int f0 = blockIdx.x * MT;
    const float* wb = wave + (size_t)b * TLEN;
    const float4* win4 = (const float4*)win;

    const int rr = w * 4 + q;          // this thread's frame row (0..31)
    const int fr = f0 + rr;
    const bool valid = fr < NFRAMES;
    const float* x = wb + (size_t)fr * FS;
    const float4* x4 = (const float4*)x;
    float ps = 0.f;                    // waveform partial sum (for mean)

    // ---- P1b: chunk0 (t 0..127): build x-only s,d tiles (272-B stride) ----
    {
        float4 v0 = {0,0,0,0}, v1 = {0,0,0,0};
        if (valid) { v0 = x4[2 * cg]; v1 = x4[2 * cg + 1]; }
        ps += v0.x + v0.y + v0.z + v0.w + v1.x + v1.y + v1.z + v1.w;
        float4 w0 = win4[2 * cg], w1 = win4[2 * cg + 1];
        float xpn = __shfl(v1.w, lane - 1);
        float xprev = (cg == 0) ? v0.x : xpn;
        float y[8];
        y[0] = (v0.x - PRE * xprev) * w0.x;
        y[1] = (v0.y - PRE * v0.x) * w0.y;
        y[2] = (v0.z - PRE * v0.y) * w0.z;
        y[3] = (v0.w - PRE * v0.z) * w0.w;
        y[4] = (v1.x - PRE * v0.w) * w1.x;
        y[5] = (v1.y - PRE * v1.x) * w1.y;
        y[6] = (v1.z - PRE * v1.y) * w1.z;
        y[7] = (v1.w - PRE * v1.z) * w1.w;

        float yr[8];
        #pragma unroll
        for (int e = 0; e < 8; ++e) yr[e] = 0.f;
        if (cg >= 14) {                      // t >= 113 folds (u = 512-t in 385..399)
            const int u0 = 512 - 8 * cg;     // 400 (cg14) or 392 (cg15)
            float4 xr0 = {0,0,0,0}, xr1 = {0,0,0,0};
            float xu0 = 0.f;
            if (valid) {
                xr0 = x4[u0 / 4 - 2]; xr1 = x4[u0 / 4 - 1];
                if (u0 <= 399) xu0 = x[u0];
            }
            ps += xr0.x + xr0.y + xr0.z + xr0.w + xr1.x + xr1.y + xr1.z + xr1.w;
            float4 wr0 = win4[u0 / 4 - 2], wr1 = win4[u0 / 4 - 1];
            float wu0 = (u0 <= 399) ? win[u0] : 0.f;
            yr[0] = (xu0   - PRE * xr1.w) * wu0;
            yr[1] = (xr1.w - PRE * xr1.z) * wr1.w;
            yr[2] = (xr1.z - PRE * xr1.y) * wr1.z;
            yr[3] = (xr1.y - PRE * xr1.x) * wr1.y;
            yr[4] = (xr1.x - PRE * xr0.w) * wr1.x;
            yr[5] = (xr0.w - PRE * xr0.z) * wr0.w;
            yr[6] = (xr0.z - PRE * xr0.y) * wr0.z;
            yr[7] = (xr0.y - PRE * xr0.x) * wr0.y;
        }
        float s8[8], d8[8];
        #pragma unroll
        for (int e = 0; e < 8; ++e) { s8[e] = y[e] + yr[e]; d8[e] = y[e] - yr[e]; }
        u32 byte = (u32)rr * 272u + (u32)cg * 16u;
        pack_write(s8, T + C0_SH, T + C0_SL, byte);
        pack_write(d8, T + C0_DH, T + C0_DL, byte);
    }
    __syncthreads();

    // ---- GEMM chunk0: Re ks 0..3 (A=s), Im ks 0..3 (A=d); wave w: bins 32w..32w+31 ----
    f32x4 accR[2][2], accI[2][2];
    #pragma unroll
    for (int mf = 0; mf < 2; ++mf)
        #pragma unroll
        for (int j = 0; j < 2; ++j) { accR[mf][j] = (f32x4)0.f; accI[mf][j] = (f32x4)0.f; }

    dft_pass<272, 2, 4, RE_KS>(T + C0_SH, T + C0_SL, wsb + OFF_REH, wsb + OFF_REL, 0, w, lane, accR);
    dft_pass<272, 2, 4, IM_KS>(T + C0_DH, T + C0_DL, wsb + OFF_IMH, wsb + OFF_IML, 0, w, lane, accI);
    __syncthreads();

    // ---- P1c: chunk1 (t 128..255 fold; s also t 256..287 tail) ----
    {
        float4 v0 = {0,0,0,0}, v1 = {0,0,0,0};
        if (valid) { v0 = x4[32 + 2 * cg]; v1 = x4[33 + 2 * cg]; }
        ps += v0.x + v0.y + v0.z + v0.w + v1.x + v1.y + v1.z + v1.w;
        float4 w0 = win4[32 + 2 * cg], w1 = win4[33 + 2 * cg];
        float xpn = __shfl(v1.w, lane - 1);
        float xprev = (cg == 0) ? (valid ? x[127] : 0.f) : xpn;
        float y[8];
        y[0] = (v0.x - PRE * xprev) * w0.x;
        y[1] = (v0.y - PRE * v0.x) * w0.y;
        y[2] = (v0.z - PRE * v0.y) * w0.z;
        y[3] = (v0.w - PRE * v0.z) * w0.w;
        y[4] = (v1.x - PRE * v0.w) * w1.x;
        y[5] = (v1.y - PRE * v1.x) * w1.y;
        y[6] = (v1.z - PRE * v1.y) * w1.z;
        y[7] = (v1.w - PRE * v1.z) * w1.w;

        const int u0 = 384 - 8 * cg;        // 264..384, all fold
        float4 xr0 = {0,0,0,0}, xr1 = {0,0,0,0};
        float xu0 = 0.f;
        if (valid) { xr0 = x4[u0 / 4 - 2]; xr1 = x4[u0 / 4 - 1]; xu0 = x[u0]; }
        ps += xr0.x + xr0.y + xr0.z + xr0.w + xr1.x + xr1.y + xr1.z + xr1.w;
        float4 wr0 = win4[u0 / 4 - 2], wr1 = win4[u0 / 4 - 1];
        float wu0 = win[u0];
        float yr[8];
        yr[0] = (xu0   - PRE * xr1.w) * wu0;
        yr[1] = (xr1.w - PRE * xr1.z) * wr1.w;
        yr[2] = (xr1.z - PRE * xr1.y) * wr1.z;
        yr[3] = (xr1.y - PRE * xr1.x) * wr1.y;
        yr[4] = (xr1.x - PRE * xr0.w) * wr1.x;
        yr[5] = (xr0.w - PRE * xr0.z) * wr0.w;
        yr[6] = (xr0.z - PRE * xr0.y) * wr0.z;
        yr[7] = (xr0.y - PRE * xr0.x) * wr0.y;

        float s8[8], d8[8];
        #pragma unroll
        for (int e = 0; e < 8; ++e) { s8[e] = y[e] + yr[e]; d8[e] = y[e] - yr[e]; }
        u32 byteS = (u32)rr * 320u + (((u32)cg * 16u) ^ ((((u32)rr >> 1) & 3u) << 4));
        u32 byteD = (u32)rr * 272u + (u32)cg * 16u;
        pack_write(s8, T + C1_SH, T + C1_SL, byteS);
        pack_write(d8, T + C1_DH, T + C1_DL, byteD);

        // finalize mean for this frame (samples 0..399 covered exactly once)
        float acc = ps;
        #pragma unroll
        for (int o = 8; o; o >>= 1) acc += __shfl_xor(acc, o);
        if (cg == 0) smean[rr] = acc * (1.0f / FL);
    }
    // s tail: cols t=256..287 (units 16..19): only t=256 nonzero (x-only)
    {
        const int trr = tid & 31;
        const int grp = tid >> 5;          // 0..15; units 16..19 served by grp<4
        if (grp < 4) {
            const int tfr = f0 + trr;
            float y256 = 0.f;
            if (grp == 0 && tfr < NFRAMES) {
                const float* tx = wb + (size_t)tfr * FS;
                y256 = (tx[256] - PRE * tx[255]) * win[256];
            }
            float s8[8] = {y256, 0.f, 0.f, 0.f, 0.f, 0.f, 0.f, 0.f};
            u32 byte = (u32)trr * 320u + ((((u32)(16 + grp)) * 16u) ^ ((((u32)trr >> 1) & 3u) << 4));
            pack_write(s8, T + C1_SH, T + C1_SL, byte);
        }
    }
    __syncthreads();

    // ---- GEMM chunk1: Re ks 4..8 (5 ks, A=s RS320 SWT1), Im ks 4..7 (A=d RS272) ----
    dft_pass<320, 1, 5, RE_KS>(T + C1_SH, T + C1_SL, wsb + OFF_REH, wsb + OFF_REL, 4, w, lane, accR);
    dft_pass<272, 2, 4, IM_KS>(T + C1_DH, T + C1_DL, wsb + OFF_IMH, wsb + OFF_IML, 4, w, lane, accI);
    __syncthreads();

    // ---- power with mean correction -> LDS bf16 [32][256] (512-B stride) ----
    {
        const float* cs = (const float*)(wsb + OFF_CS);
        #pragma unroll
        for (int mf = 0; mf < 2; ++mf)
            #pragma unroll
            for (int j = 0; j < 2; ++j) {
                const u32 bin = (u32)(32 * w + j * 16 + cg);
                const float Cb = cs[bin], Sb = cs[256 + bin];
                #pragma unroll
                for (int r = 0; r < 4; ++r) {
                    u32 row = (u32)(mf * 16 + (q << 2) + r);
                    const float mcr = (1.0f - PRE) * smean[row];
                    float pR = accR[mf][j][r] - mcr * Cb;
                    float pI = accI[mf][j][r] - mcr * Sb;
                    float pw = pR * pR + pI * pI;
                    u32 byte = (row * 512u + bin * 2u) ^ ((row & 7u) << 4);
                    *(u16*)(T + byte) = f2bf(pw);
                }
            }
    }
    __syncthreads();

    // ---- mel GEMM (M=32, N=96 padded, K=256): 6 combos on waves 0..5 ----
    const u16* melb = wsb + OFF_MEL;
    if (w < 6) {
        const int mfm = w & 1;             // rows mfm*16..+15
        const int nf0 = (w >> 1) * 2;      // frag pair {nf0, nf0+1}, nf0 in {0,2,4}
        f32x4 accM[2];
        #pragma unroll
        for (int j = 0; j < 2; ++j) accM[j] = (f32x4)0.f;
        for (int ks = 0; ks < 8; ++ks) {
            u32 row = (u32)(mfm * 16 + cg);
            u32 byte = (row * 512u + (u32)(ks * 32 + (q << 3)) * 2u) ^ ((row & 7u) << 4);
            bf16x8 aP = *(const bf16x8*)(T + byte);
            #pragma unroll
            for (int j = 0; j < 2; ++j) {
                bf16x8 bM = *(const bf16x8*)(melb + ((size_t)((nf0 + j) * 8 + ks) * 64 + lane) * 8);
                accM[j] = __builtin_amdgcn_mfma_f32_16x16x32_bf16(aP, bM, accM[j], 0, 0, 0);
            }
        }
        #pragma unroll
        for (int j = 0; j < 2; ++j) {
            const int m = (nf0 + j) * 16 + cg;
            #pragma unroll
            for (int r = 0; r < 4; ++r) {
                const int rowl = mfm * 16 + (q << 2) + r;
                const int ofr = f0 + rowl;
                if (ofr < NFRAMES && m < NM) {
                    float v = fmaxf(accM[j][r] + EPSF, EPSF);
                    out[((size_t)b * NFRAMES + ofr) * NM + m] = logf(v);
                }
            }
        }
    }
}

// ---------------- fallback (fp32 kernel, used if ws too small) ----------------
#define TFB 16
#define NB 256
__global__ __launch_bounds__(256, 3) void fbank_fallback(
    const float* __restrict__ wave, const float* __restrict__ win,
    const float* __restrict__ dftr, const float* __restrict__ dfti,
    const float* __restrict__ melw, float* __restrict__ out) {
    __shared__ float s_fr[TFB][PW];
    __shared__ float s_pw[TFB][NB + 1];
    const int tid = threadIdx.x, wv = tid >> 6, lane = tid & 63;
    const int fbase = blockIdx.x * TFB;
    #pragma unroll
    for (int j = 0; j < TFB / 4; ++j) {
        const int lf = wv * (TFB / 4) + j;
        const int gid = fbase + lf;
        const int bb = gid / NFRAMES;
        const int fr = gid - bb * NFRAMES;
        const float* x = wave + (size_t)bb * TLEN + (size_t)fr * FS;
        float s = 0.f;
        for (int i = lane; i < FL; i += 64) s += x[i];
        #pragma unroll
        for (int off = 32; off >= 1; off >>= 1) s += __shfl_xor(s, off);
        const float mean = s * (1.0f / FL);
        for (int i = lane; i < FL; i += 64) {
            const float xi = x[i];
            const float xm = (i == 0) ? xi : x[i - 1];
            s_fr[lf][i] = (xi - PRE * xm - (1.0f - PRE) * mean) * win[i];
        }
        for (int i = FL + lane; i < PW; i += 64) s_fr[lf][i] = 0.f;
    }
    __syncthreads();
    {
        const int bin = tid;
        const float4* dr4 = (const float4*)(dftr + (size_t)bin * PW);
        const float4* di4 = (const float4*)(dfti + (size_t)bin * PW);
        float accr[TFB], acci[TFB];
        #pragma unroll
        for (int f = 0; f < TFB; ++f) { accr[f] = 0.f; acci[f] = 0.f; }
        for (int k4 = 0; k4 < PW / 4; ++k4) {
            const float4 r = dr4[k4], im = di4[k4];
            #pragma unroll
            for (int f = 0; f < TFB; ++f) {
                const float4 fr = *(const float4*)&s_fr[f][k4 * 4];
                accr[f] += fr.x * r.x + fr.y * r.y + fr.z * r.z + fr.w * r.w;
                acci[f] += fr.x * im.x + fr.y * im.y + fr.z * im.z + fr.w * im.w;
            }
        }
        #pragma unroll
        for (int f = 0; f < TFB; ++f) s_pw[f][bin] = accr[f] * accr[f] + acci[f] * acci[f];
    }
    __syncthreads();
    for (int o = tid; o < TFB * NM; o += 256) {
        const int f = o / NM, m = o - f * NM;
        const float* wm = melw + (size_t)m * 257;
        float acc = 0.f;
        for (int k = 0; k < NB; ++k) acc += s_pw[f][k] * wm[k];
        out[(size_t)(fbase + f) * NM + m] = logf(fmaxf(acc + EPSF, EPSF));
    }
}

extern "C" void kernel_launch(void* const* d_in, const int* in_sizes, int n_in,
                              void* d_out, int out_size, void* d_ws, size_t ws_size,
                              hipStream_t stream) {
    const float* wave = (const float*)d_in[0];
    const float* win  = (const float*)d_in[1];
    const float* dftr = (const float*)d_in[2];
    const float* dfti = (const float*)d_in[3];
    const float* melw = (const float*)d_in[4];
    float* out = (float*)d_out;

    if (ws_size >= WS_NEED) {
        u16* wsb = (u16*)d_ws;
        const int prep_threads = 16 * RE_KS * 64 + 16 * IM_KS * 64 + 6 * 8 * 64;  // 20480
        prep_kernel<<<(prep_threads + 255) / 256, 256, 0, stream>>>(dftr, dfti, melw, wsb);
        prep_cs_kernel<<<128, 256, 0, stream>>>(dftr, dfti, win, wsb);   // 512 waves, 1/bin
        dim3 grid(NTILES, BATCH);
        fbank_mfma<<<grid, 512, 0, stream>>>(wave, win, wsb, out);
    } else {
        const int nblocks = (BATCH * NFRAMES) / TFB;
        fbank_fallback<<<nblocks, 256, 0, stream>>>(wave, win, dftr, dfti, melw, out);
    }
}

// Round 16
// 117.371 us; speedup vs baseline: 1.3133x; 1.0149x over previous
//
#include <hip/hip_runtime.h>
#include <math.h>

// Fbank via split-bf16 MFMA + real-DFT folding. R16 = R15 +
// (1) v_cvt_pk_bf16_f32 packing (1 inst per bf16-pair vs ~11 scalar ops) and
// (2) fused RE+IM GEMM per chunk: one interleaved loop keeps the B ping-pong
// prefetch chain unbroken across components (4 pipeline restarts -> 2).

#define BATCH 32
#define TLEN 480000
#define NFRAMES 2998
#define FL 400
#define FS 160
#define PW 512
#define NM 80
#define MT 32                // frames per block
#define NTILES 94            // ceil(2998/32)
#define PRE 0.97f
#define EPSF 1e-6f

#define RE_KS 9              // K=288 (t 0..256 + pad)
#define IM_KS 8              // K=256 (t 0..255)
#define RE_U16 (16 * RE_KS * 64 * 8)   // 73728
#define IM_U16 (16 * IM_KS * 64 * 8)   // 65536
#define MEL_U16 (6 * 8 * 64 * 8)       // 24576
#define OFF_REH 0
#define OFF_REL RE_U16
#define OFF_IMH (2 * RE_U16)
#define OFF_IML (2 * RE_U16 + IM_U16)
#define OFF_MEL (2 * RE_U16 + 2 * IM_U16)
#define OFF_CS  (OFF_MEL + MEL_U16)          // u16 units; 512 floats follow
#define WS_NEED ((size_t)OFF_CS * 2 + 512 * 4)   // ~608 KB

// LDS tile byte offsets. 128-col tiles: 272-B row stride (natural bank
// rotation, no XOR). 160-col chunk1 s-tile: 320-B stride + SWT1 XOR.
#define C0_SH 0
#define C0_SL 8704
#define C0_DH 17408
#define C0_DL 26112          // chunk0 total 34,816 B
#define C1_SH 0
#define C1_SL 10240
#define C1_DH 20480
#define C1_DL 29184          // chunk1 total 37,888 B

typedef short bf16x8 __attribute__((ext_vector_type(8)));
typedef float f32x4 __attribute__((ext_vector_type(4)));
typedef unsigned int u32;
typedef unsigned short u16;
typedef u32 u32x4 __attribute__((ext_vector_type(4)));

__device__ __forceinline__ u16 f2bf(float f) {
    u32 u = __builtin_bit_cast(u32, f);
    return (u16)((u + 0x7FFFu + ((u >> 16) & 1u)) >> 16);
}
__device__ __forceinline__ float bf2f(u16 h) {
    u32 u = ((u32)h) << 16;
    return __builtin_bit_cast(float, u);
}
// packed bf16 convert: src0 -> low half, src1 -> high half
__device__ __forceinline__ u32 cvtpk2(float lo, float hi) {
    u32 r;
    asm("v_cvt_pk_bf16_f32 %0, %1, %2" : "=v"(r) : "v"(lo), "v"(hi));
    return r;
}

// ---------------- prep: folded B (cos/sin hi+lo) + mel ----------------
__global__ void prep_kernel(const float* __restrict__ dftr, const float* __restrict__ dfti,
                            const float* __restrict__ melw, u16* __restrict__ wsb) {
    int idx = blockIdx.x * 256 + threadIdx.x;
    if (idx < 16 * RE_KS * 64) {                       // 9216 Re groups
        int nf = idx / (RE_KS * 64);
        int rem = idx - nf * (RE_KS * 64);
        int ks = rem >> 6, l = rem & 63;
        int f = nf * 16 + (l & 15);
        int k = ks * 32 + ((l >> 4) << 3);
        u16* dh = wsb + OFF_REH + (size_t)idx * 8;
        u16* dl = wsb + OFF_REL + (size_t)idx * 8;
        #pragma unroll
        for (int e = 0; e < 8; ++e) {
            int kk = k + e;
            float x = (kk <= 256) ? dftr[(size_t)f * PW + kk] : 0.f;
            u16 h = f2bf(x);
            dh[e] = h;
            dl[e] = f2bf(x - bf2f(h));
        }
    } else if (idx < 16 * RE_KS * 64 + 16 * IM_KS * 64) {   // 8192 Im groups
        int j = idx - 16 * RE_KS * 64;
        int nf = j / (IM_KS * 64);
        int rem = j - nf * (IM_KS * 64);
        int ks = rem >> 6, l = rem & 63;
        int f = nf * 16 + (l & 15);
        int k = ks * 32 + ((l >> 4) << 3);
        u16* dh = wsb + OFF_IMH + (size_t)j * 8;
        u16* dl = wsb + OFF_IML + (size_t)j * 8;
        #pragma unroll
        for (int e = 0; e < 8; ++e) {
            float x = dfti[(size_t)f * PW + k + e];    // k+e <= 255
            u16 h = f2bf(x);
            dh[e] = h;
            dl[e] = f2bf(x - bf2f(h));
        }
    } else {                                            // mel groups
        int m = idx - (16 * RE_KS * 64 + 16 * IM_KS * 64);
        if (m < 6 * 8 * 64) {
            int nf = m / (8 * 64);
            int ks = (m >> 6) & 7, l = m & 63;
            int n = nf * 16 + (l & 15);
            int k = ks * 32 + ((l >> 4) << 3);
            u16* dst = wsb + OFF_MEL + (size_t)m * 8;
            #pragma unroll
            for (int e = 0; e < 8; ++e)
                dst[e] = (n < NM) ? f2bf(melw[(size_t)n * 257 + k + e]) : (u16)0;
        }
    }
}

// ---------------- prep C/S: one wave per bin (512 waves) ----------------
__global__ void prep_cs_kernel(const float* __restrict__ dftr, const float* __restrict__ dfti,
                               const float* __restrict__ win, u16* __restrict__ wsb) {
    const int gw = (blockIdx.x * 256 + threadIdx.x) >> 6;   // 0..511
    const int lane = threadIdx.x & 63;
    float* cs = (float*)(wsb + OFF_CS);
    float acc = 0.f;
    if (gw < 256) {
        const int f = gw;
        for (int t = lane; t <= 256; t += 64) {
            float wt = (t < FL) ? win[t] : 0.f;
            float wu = (t >= 1 && t < 256 && (512 - t) < FL) ? win[512 - t] : 0.f;
            acc += (wt + wu) * dftr[(size_t)f * PW + t];
        }
    } else {
        const int ff = gw - 256;
        for (int t = lane; t <= 255; t += 64) {
            float wt = (t < FL) ? win[t] : 0.f;
            float wu = (t >= 1 && (512 - t) < FL) ? win[512 - t] : 0.f;
            acc += (wt - wu) * dfti[(size_t)ff * PW + t];
        }
    }
    #pragma unroll
    for (int o = 32; o; o >>= 1) acc += __shfl_xor(acc, o);
    if (lane == 0) cs[gw] = acc;
}

// swizzle select: 0 -> (r&7)<<4 (512-B stride), 1 -> ((r>>1)&3)<<4 (320-B), 2 -> none (272-B)
__device__ __forceinline__ u32 swz(int SWT, u32 r) {
    return (SWT == 0) ? ((r & 7u) << 4) : (SWT == 1) ? (((r >> 1) & 3u) << 4) : 0u;
}

// 6 MFMA for one (bh,bl) ping-pong slot: 2 m-frags x 3 split-product terms
#define MFMA6X(ACC, AH, AL, D, J)                                                          \
    _Pragma("unroll")                                                                      \
    for (int mf = 0; mf < 2; ++mf) {                                                       \
        ACC[mf][J] = __builtin_amdgcn_mfma_f32_16x16x32_bf16(AH[mf], D[0], ACC[mf][J], 0, 0, 0); \
        ACC[mf][J] = __builtin_amdgcn_mfma_f32_16x16x32_bf16(AL[mf], D[0], ACC[mf][J], 0, 0, 0); \
        ACC[mf][J] = __builtin_amdgcn_mfma_f32_16x16x32_bf16(AH[mf], D[1], ACC[mf][J], 0, 0, 0); \
    }

// ---------------- fused RE+IM DFT pass: unbroken B ping-pong across components ----------------
template<int RS_S, int SWT_S, int RS_D, int SWT_D, int NIM, int NRE>
__device__ __forceinline__ void dft_fused(
    const char* tSH, const char* tSL, const char* tDH, const char* tDL,
    const u16* __restrict__ bRH, const u16* __restrict__ bRL,
    const u16* __restrict__ bIH, const u16* __restrict__ bIL,
    int ks0, int w, int lane, f32x4 (&accR)[2][2], f32x4 (&accI)[2][2]) {

    bf16x8 sH[2], sL[2], dH[2], dL[2], Ba[2], Bb[2];

#define LDA_X(TH, TL, RS, SWT, KS, AH, AL)                                     \
    { _Pragma("unroll")                                                        \
      for (int mf = 0; mf < 2; ++mf) {                                         \
        u32 r = (u32)(mf * 16 + (lane & 15));                                  \
        u32 off = (u32)((KS) * 64 + ((lane >> 4) << 4));                       \
        u32 byte = r * (RS) + (off ^ swz(SWT, r));                             \
        AH[mf] = *(const bf16x8*)((TH) + byte);                                \
        AL[mf] = *(const bf16x8*)((TL) + byte);                                \
      } }
#define LDB_X(BH, BL, BKS, KSG, J, D)                                          \
    {                                                                          \
        size_t o = ((size_t)((2 * w + (J)) * (BKS) + (KSG)) * 64 + lane) * 8;  \
        D[0] = *(const bf16x8*)((BH) + o);                                     \
        D[1] = *(const bf16x8*)((BL) + o);                                     \
    }

    LDB_X(bRH, bRL, RE_KS, ks0, 0, Ba);
    #pragma unroll
    for (int ks = 0; ks < NIM; ++ks) {
        LDA_X(tSH, tSL, RS_S, SWT_S, ks, sH, sL);
        LDB_X(bRH, bRL, RE_KS, ks0 + ks, 1, Bb);
        MFMA6X(accR, sH, sL, Ba, 0);
        LDB_X(bIH, bIL, IM_KS, ks0 + ks, 0, Ba);
        MFMA6X(accR, sH, sL, Bb, 1);
        LDA_X(tDH, tDL, RS_D, SWT_D, ks, dH, dL);
        LDB_X(bIH, bIL, IM_KS, ks0 + ks, 1, Bb);
        MFMA6X(accI, dH, dL, Ba, 0);
        if (ks + 1 < NIM) { LDB_X(bRH, bRL, RE_KS, ks0 + ks + 1, 0, Ba); }
        else if (NRE > NIM) { LDB_X(bRH, bRL, RE_KS, ks0 + NIM, 0, Ba); }
        MFMA6X(accI, dH, dL, Bb, 1);
    }
    #pragma unroll
    for (int ks = NIM; ks < NRE; ++ks) {      // extra RE-only k-steps (chunk1)
        LDA_X(tSH, tSL, RS_S, SWT_S, ks, sH, sL);
        LDB_X(bRH, bRL, RE_KS, ks0 + ks, 1, Bb);
        MFMA6X(accR, sH, sL, Ba, 0);
        if (ks + 1 < NRE) LDB_X(bRH, bRL, RE_KS, ks0 + ks + 1, 0, Ba);
        MFMA6X(accR, sH, sL, Bb, 1);
    }
#undef LDA_X
#undef LDB_X
}

__device__ __forceinline__ void pack_write(const float* ys, char* baseH, char* baseL, u32 byte) {
    u32x4 hv, lv;
    #pragma unroll
    for (int e = 0; e < 4; ++e) {
        float y0 = ys[2 * e], y1 = ys[2 * e + 1];
        u32 h = cvtpk2(y0, y1);
        hv[e] = h;
        float h0 = __builtin_bit_cast(float, h << 16);
        float h1 = __builtin_bit_cast(float, h & 0xFFFF0000u);
        lv[e] = cvtpk2(y0 - h0, y1 - h1);
    }
    *(u32x4*)(baseH + byte) = hv;
    *(u32x4*)(baseL + byte) = lv;
}

// ---------------- main fused kernel (512 threads / 8 waves) ----------------
__global__ __launch_bounds__(512, 4) void fbank_mfma(
    const float* __restrict__ wave, const float* __restrict__ win,
    const u16* __restrict__ wsb, float* __restrict__ out) {
    __shared__ float smean[MT];
    __shared__ u16 stile[18944];       // 37,888 B tile buffer (power overlay fits)
    char* T = (char*)stile;

    const int tid = threadIdx.x, w = tid >> 6, lane = tid & 63;
    const int q = lane >> 4;           // frame sub-row within wave (4 frames/wave)
    const int cg = lane & 15;          // col-group
    const int b = blockIdx.y;
    const int f0 = blockIdx.x * MT;
    const float* wb = wave + (size_t)b * TLEN;
    const float4* win4 = (const float4*)win;

    const int rr = w * 4 + q;          // this thread's frame row (0..31)
    const int fr = f0 + rr;
    const bool valid = fr < NFRAMES;
    const float* x = wb + (size_t)fr * FS;
    const float4* x4 = (const float4*)x;
    float ps = 0.f;                    // waveform partial sum (for mean)

    // ---- P1b: chunk0 (t 0..127): build x-only s,d tiles (272-B stride) ----
    {
        float4 v0 = {0,0,0,0}, v1 = {0,0,0,0};
        if (valid) { v0 = x4[2 * cg]; v1 = x4[2 * cg + 1]; }
        ps += v0.x + v0.y + v0.z + v0.w + v1.x + v1.y + v1.z + v1.w;
        float4 w0 = win4[2 * cg], w1 = win4[2 * cg + 1];
        float xpn = __shfl(v1.w, lane - 1);
        float xprev = (cg == 0) ? v0.x : xpn;
        float y[8];
        y[0] = (v0.x - PRE * xprev) * w0.x;
        y[1] = (v0.y - PRE * v0.x) * w0.y;
        y[2] = (v0.z - PRE * v0.y) * w0.z;
        y[3] = (v0.w - PRE * v0.z) * w0.w;
        y[4] = (v1.x - PRE * v0.w) * w1.x;
        y[5] = (v1.y - PRE * v1.x) * w1.y;
        y[6] = (v1.z - PRE * v1.y) * w1.z;
        y[7] = (v1.w - PRE * v1.z) * w1.w;

        float yr[8];
        #pragma unroll
        for (int e = 0; e < 8; ++e) yr[e] = 0.f;
        if (cg >= 14) {                      // t >= 113 folds (u = 512-t in 385..399)
            const int u0 = 512 - 8 * cg;     // 400 (cg14) or 392 (cg15)
            float4 xr0 = {0,0,0,0}, xr1 = {0,0,0,0};
            float xu0 = 0.f;
            if (valid) {
                xr0 = x4[u0 / 4 - 2]; xr1 = x4[u0 / 4 - 1];
                if (u0 <= 399) xu0 = x[u0];
            }
            ps += xr0.x + xr0.y + xr0.z + xr0.w + xr1.x + xr1.y + xr1.z + xr1.w;
            float4 wr0 = win4[u0 / 4 - 2], wr1 = win4[u0 / 4 - 1];
            float wu0 = (u0 <= 399) ? win[u0] : 0.f;
            yr[0] = (xu0   - PRE * xr1.w) * wu0;
            yr[1] = (xr1.w - PRE * xr1.z) * wr1.w;
            yr[2] = (xr1.z - PRE * xr1.y) * wr1.z;
            yr[3] = (xr1.y - PRE * xr1.x) * wr1.y;
            yr[4] = (xr1.x - PRE * xr0.w) * wr1.x;
            yr[5] = (xr0.w - PRE * xr0.z) * wr0.w;
            yr[6] = (xr0.z - PRE * xr0.y) * wr0.z;
            yr[7] = (xr0.y - PRE * xr0.x) * wr0.y;
        }
        float s8[8], d8[8];
        #pragma unroll
        for (int e = 0; e < 8; ++e) { s8[e] = y[e] + yr[e]; d8[e] = y[e] - yr[e]; }
        u32 byte = (u32)rr * 272u + (u32)cg * 16u;
        pack_write(s8, T + C0_SH, T + C0_SL, byte);
        pack_write(d8, T + C0_DH, T + C0_DL, byte);
    }
    __syncthreads();

    // ---- GEMM chunk0 (fused RE+IM, ks 0..3); wave w: bins 32w..32w+31 ----
    f32x4 accR[2][2], accI[2][2];
    #pragma unroll
    for (int mf = 0; mf < 2; ++mf)
        #pragma unroll
        for (int j = 0; j < 2; ++j) { accR[mf][j] = (f32x4)0.f; accI[mf][j] = (f32x4)0.f; }

    dft_fused<272, 2, 272, 2, 4, 4>(T + C0_SH, T + C0_SL, T + C0_DH, T + C0_DL,
                                    wsb + OFF_REH, wsb + OFF_REL, wsb + OFF_IMH, wsb + OFF_IML,
                                    0, w, lane, accR, accI);
    __syncthreads();

    // ---- P1c: chunk1 (t 128..255 fold; s also t 256..287 tail) ----
    {
        float4 v0 = {0,0,0,0}, v1 = {0,0,0,0};
        if (valid) { v0 = x4[32 + 2 * cg]; v1 = x4[33 + 2 * cg]; }
        ps += v0.x + v0.y + v0.z + v0.w + v1.x + v1.y + v1.z + v1.w;
        float4 w0 = win4[32 + 2 * cg], w1 = win4[33 + 2 * cg];
        float xpn = __shfl(v1.w, lane - 1);
        float xprev = (cg == 0) ? (valid ? x[127] : 0.f) : xpn;
        float y[8];
        y[0] = (v0.x - PRE * xprev) * w0.x;
        y[1] = (v0.y - PRE * v0.x) * w0.y;
        y[2] = (v0.z - PRE * v0.y) * w0.z;
        y[3] = (v0.w - PRE * v0.z) * w0.w;
        y[4] = (v1.x - PRE * v0.w) * w1.x;
        y[5] = (v1.y - PRE * v1.x) * w1.y;
        y[6] = (v1.z - PRE * v1.y) * w1.z;
        y[7] = (v1.w - PRE * v1.z) * w1.w;

        const int u0 = 384 - 8 * cg;        // 264..384, all fold
        float4 xr0 = {0,0,0,0}, xr1 = {0,0,0,0};
        float xu0 = 0.f;
        if (valid) { xr0 = x4[u0 / 4 - 2]; xr1 = x4[u0 / 4 - 1]; xu0 = x[u0]; }
        ps += xr0.x + xr0.y + xr0.z + xr0.w + xr1.x + xr1.y + xr1.z + xr1.w;
        float4 wr0 = win4[u0 / 4 - 2], wr1 = win4[u0 / 4 - 1];
        float wu0 = win[u0];
        float yr[8];
        yr[0] = (xu0   - PRE * xr1.w) * wu0;
        yr[1] = (xr1.w - PRE * xr1.z) * wr1.w;
        yr[2] = (xr1.z - PRE * xr1.y) * wr1.z;
        yr[3] = (xr1.y - PRE * xr1.x) * wr1.y;
        yr[4] = (xr1.x - PRE * xr0.w) * wr1.x;
        yr[5] = (xr0.w - PRE * xr0.z) * wr0.w;
        yr[6] = (xr0.z - PRE * xr0.y) * wr0.z;
        yr[7] = (xr0.y - PRE * xr0.x) * wr0.y;

        float s8[8], d8[8];
        #pragma unroll
        for (int e = 0; e < 8; ++e) { s8[e] = y[e] + yr[e]; d8[e] = y[e] - yr[e]; }
        u32 byteS = (u32)rr * 320u + (((u32)cg * 16u) ^ ((((u32)rr >> 1) & 3u) << 4));
        u32 byteD = (u32)rr * 272u + (u32)cg * 16u;
        pack_write(s8, T + C1_SH, T + C1_SL, byteS);
        pack_write(d8, T + C1_DH, T + C1_DL, byteD);

        // finalize mean for this frame (samples 0..399 covered exactly once)
        float acc = ps;
        #pragma unroll
        for (int o = 8; o; o >>= 1) acc += __shfl_xor(acc, o);
        if (cg == 0) smean[rr] = acc * (1.0f / FL);
    }
    // s tail: cols t=256..287 (units 16..19): only t=256 nonzero (x-only)
    {
        const int trr = tid & 31;
        const int grp = tid >> 5;          // 0..15; units 16..19 served by grp<4
        if (grp < 4) {
            const int tfr = f0 + trr;
            float y256 = 0.f;
            if (grp == 0 && tfr < NFRAMES) {
                const float* tx = wb + (size_t)tfr * FS;
                y256 = (tx[256] - PRE * tx[255]) * win[256];
            }
            float s8[8] = {y256, 0.f, 0.f, 0.f, 0.f, 0.f, 0.f, 0.f};
            u32 byte = (u32)trr * 320u + ((((u32)(16 + grp)) * 16u) ^ ((((u32)trr >> 1) & 3u) << 4));
            pack_write(s8, T + C1_SH, T + C1_SL, byte);
        }
    }
    __syncthreads();

    // ---- GEMM chunk1 (fused RE+IM; RE ks 4..8, IM ks 4..7) ----
    dft_fused<320, 1, 272, 2, 4, 5>(T + C1_SH, T + C1_SL, T + C1_DH, T + C1_DL,
                                    wsb + OFF_REH, wsb + OFF_REL, wsb + OFF_IMH, wsb + OFF_IML,
                                    4, w, lane, accR, accI);
    __syncthreads();

    // ---- power with mean correction -> LDS bf16 [32][256] (512-B stride) ----
    {
        const float* cs = (const float*)(wsb + OFF_CS);
        #pragma unroll
        for (int mf = 0; mf < 2; ++mf)
            #pragma unroll
            for (int j = 0; j < 2; ++j) {
                const u32 bin = (u32)(32 * w + j * 16 + cg);
                const float Cb = cs[bin], Sb = cs[256 + bin];
                #pragma unroll
                for (int r = 0; r < 4; ++r) {
                    u32 row = (u32)(mf * 16 + (q << 2) + r);
                    const float mcr = (1.0f - PRE) * smean[row];
                    float pR = accR[mf][j][r] - mcr * Cb;
                    float pI = accI[mf][j][r] - mcr * Sb;
                    float pw = pR * pR + pI * pI;
                    u32 byte = (row * 512u + bin * 2u) ^ ((row & 7u) << 4);
                    *(u16*)(T + byte) = f2bf(pw);
                }
            }
    }
    __syncthreads();

    // ---- mel GEMM (M=32, N=96 padded, K=256): 6 combos on waves 0..5 ----
    const u16* melb = wsb + OFF_MEL;
    if (w < 6) {
        const int mfm = w & 1;             // rows mfm*16..+15
        const int nf0 = (w >> 1) * 2;      // frag pair {nf0, nf0+1}, nf0 in {0,2,4}
        f32x4 accM[2];
        #pragma unroll
        for (int j = 0; j < 2; ++j) accM[j] = (f32x4)0.f;
        for (int ks = 0; ks < 8; ++ks) {
            u32 row = (u32)(mfm * 16 + cg);
            u32 byte = (row * 512u + (u32)(ks * 32 + (q << 3)) * 2u) ^ ((row & 7u) << 4);
            bf16x8 aP = *(const bf16x8*)(T + byte);
            #pragma unroll
            for (int j = 0; j < 2; ++j) {
                bf16x8 bM = *(const bf16x8*)(melb + ((size_t)((nf0 + j) * 8 + ks) * 64 + lane) * 8);
                accM[j] = __builtin_amdgcn_mfma_f32_16x16x32_bf16(aP, bM, accM[j], 0, 0, 0);
            }
        }
        #pragma unroll
        for (int j = 0; j < 2; ++j) {
            const int m = (nf0 + j) * 16 + cg;
            #pragma unroll
            for (int r = 0; r < 4; ++r) {
                const int rowl = mfm * 16 + (q << 2) + r;
                const int ofr = f0 + rowl;
                if (ofr < NFRAMES && m < NM) {
                    float v = fmaxf(accM[j][r] + EPSF, EPSF);
                    out[((size_t)b * NFRAMES + ofr) * NM + m] = logf(v);
                }
            }
        }
    }
}

// ---------------- fallback (fp32 kernel, used if ws too small) ----------------
#define TFB 16
#define NB 256
__global__ __launch_bounds__(256, 3) void fbank_fallback(
    const float* __restrict__ wave, const float* __restrict__ win,
    const float* __restrict__ dftr, const float* __restrict__ dfti,
    const float* __restrict__ melw, float* __restrict__ out) {
    __shared__ float s_fr[TFB][PW];
    __shared__ float s_pw[TFB][NB + 1];
    const int tid = threadIdx.x, wv = tid >> 6, lane = tid & 63;
    const int fbase = blockIdx.x * TFB;
    #pragma unroll
    for (int j = 0; j < TFB / 4; ++j) {
        const int lf = wv * (TFB / 4) + j;
        const int gid = fbase + lf;
        const int bb = gid / NFRAMES;
        const int fr = gid - bb * NFRAMES;
        const float* x = wave + (size_t)bb * TLEN + (size_t)fr * FS;
        float s = 0.f;
        for (int i = lane; i < FL; i += 64) s += x[i];
        #pragma unroll
        for (int off = 32; off >= 1; off >>= 1) s += __shfl_xor(s, off);
        const float mean = s * (1.0f / FL);
        for (int i = lane; i < FL; i += 64) {
            const float xi = x[i];
            const float xm = (i == 0) ? xi : x[i - 1];
            s_fr[lf][i] = (xi - PRE * xm - (1.0f - PRE) * mean) * win[i];
        }
        for (int i = FL + lane; i < PW; i += 64) s_fr[lf][i] = 0.f;
    }
    __syncthreads();
    {
        const int bin = tid;
        const float4* dr4 = (const float4*)(dftr + (size_t)bin * PW);
        const float4* di4 = (const float4*)(dfti + (size_t)bin * PW);
        float accr[TFB], acci[TFB];
        #pragma unroll
        for (int f = 0; f < TFB; ++f) { accr[f] = 0.f; acci[f] = 0.f; }
        for (int k4 = 0; k4 < PW / 4; ++k4) {
            const float4 r = dr4[k4], im = di4[k4];
            #pragma unroll
            for (int f = 0; f < TFB; ++f) {
                const float4 fr = *(const float4*)&s_fr[f][k4 * 4];
                accr[f] += fr.x * r.x + fr.y * r.y + fr.z * r.z + fr.w * r.w;
                acci[f] += fr.x * im.x + fr.y * im.y + fr.z * im.z + fr.w * im.w;
            }
        }
        #pragma unroll
        for (int f = 0; f < TFB; ++f) s_pw[f][bin] = accr[f] * accr[f] + acci[f] * acci[f];
    }
    __syncthreads();
    for (int o = tid; o < TFB * NM; o += 256) {
        const int f = o / NM, m = o - f * NM;
        const float* wm = melw + (size_t)m * 257;
        float acc = 0.f;
        for (int k = 0; k < NB; ++k) acc += s_pw[f][k] * wm[k];
        out[(size_t)(fbase + f) * NM + m] = logf(fmaxf(acc + EPSF, EPSF));
    }
}

extern "C" void kernel_launch(void* const* d_in, const int* in_sizes, int n_in,
                              void* d_out, int out_size, void* d_ws, size_t ws_size,
                              hipStream_t stream) {
    const float* wave = (const float*)d_in[0];
    const float* win  = (const float*)d_in[1];
    const float* dftr = (const float*)d_in[2];
    const float* dfti = (const float*)d_in[3];
    const float* melw = (const float*)d_in[4];
    float* out = (float*)d_out;

    if (ws_size >= WS_NEED) {
        u16* wsb = (u16*)d_ws;
        const int prep_threads = 16 * RE_KS * 64 + 16 * IM_KS * 64 + 6 * 8 * 64;  // 20480
        prep_kernel<<<(prep_threads + 255) / 256, 256, 0, stream>>>(dftr, dfti, melw, wsb);
        prep_cs_kernel<<<128, 256, 0, stream>>>(dftr, dfti, win, wsb);   // 512 waves, 1/bin
        dim3 grid(NTILES, BATCH);
        fbank_mfma<<<grid, 512, 0, stream>>>(wave, win, wsb, out);
    } else {
        const int nblocks = (BATCH * NFRAMES) / TFB;
        fbank_fallback<<<nblocks, 256, 0, stream>>>(wave, win, dftr, dfti, melw, out);
    }
}

// Round 17
// 113.768 us; speedup vs baseline: 1.3548x; 1.0317x over previous
//
#include <hip/hip_runtime.h>
#include <math.h>

// Fbank via split-bf16 MFMA + real-DFT folding. R17: MT=48 (1.5x frames/block)
// -> B-fragment L2 traffic x0.67 and 9 MFMA per B ping-pong slot (per-CU L2
// demand ~45 B/cyc < ~56 supply; MT=32 was ~68 = over the ceiling).
// acc = 48 AGPR + ~65 arch stays under the (512,4) 128-reg cap; occupancy
// unchanged (2 blocks/CU, 16 waves). RE+IM fusion reverted (register diet).

#define BATCH 32
#define TLEN 480000
#define NFRAMES 2998
#define FL 400
#define FS 160
#define PW 512
#define NM 80
#define MT 48                // frames per block
#define NTILES 63            // ceil(2998/48)
#define PRE 0.97f
#define EPSF 1e-6f

#define RE_KS 9              // K=288 (t 0..256 + pad)
#define IM_KS 8              // K=256 (t 0..255)
#define RE_U16 (16 * RE_KS * 64 * 8)   // 73728
#define IM_U16 (16 * IM_KS * 64 * 8)   // 65536
#define MEL_U16 (6 * 8 * 64 * 8)       // 24576
#define OFF_REH 0
#define OFF_REL RE_U16
#define OFF_IMH (2 * RE_U16)
#define OFF_IML (2 * RE_U16 + IM_U16)
#define OFF_MEL (2 * RE_U16 + 2 * IM_U16)
#define OFF_CS  (OFF_MEL + MEL_U16)          // u16 units; 512 floats follow
#define WS_NEED ((size_t)OFF_CS * 2 + 512 * 4)   // ~608 KB

// LDS tile byte offsets (48 rows). 272-B stride tiles: natural bank rotation,
// no XOR. 320-B chunk1 s-tile: SWT1 XOR.
#define C0_SH 0
#define C0_SL 13056
#define C0_DH 26112
#define C0_DL 39168          // chunk0 total 52,224 B
#define C1_SH 0
#define C1_SL 15360
#define C1_DH 30720
#define C1_DL 43776          // chunk1 total 56,832 B

typedef short bf16x8 __attribute__((ext_vector_type(8)));
typedef float f32x4 __attribute__((ext_vector_type(4)));
typedef unsigned int u32;
typedef unsigned short u16;
typedef u32 u32x4 __attribute__((ext_vector_type(4)));

__device__ __forceinline__ u16 f2bf(float f) {
    u32 u = __builtin_bit_cast(u32, f);
    return (u16)((u + 0x7FFFu + ((u >> 16) & 1u)) >> 16);
}
__device__ __forceinline__ float bf2f(u16 h) {
    u32 u = ((u32)h) << 16;
    return __builtin_bit_cast(float, u);
}
// packed bf16 convert: src0 -> low half, src1 -> high half
__device__ __forceinline__ u32 cvtpk2(float lo, float hi) {
    u32 r;
    asm("v_cvt_pk_bf16_f32 %0, %1, %2" : "=v"(r) : "v"(lo), "v"(hi));
    return r;
}

// ---------------- prep: folded B (cos/sin hi+lo) + mel ----------------
__global__ void prep_kernel(const float* __restrict__ dftr, const float* __restrict__ dfti,
                            const float* __restrict__ melw, u16* __restrict__ wsb) {
    int idx = blockIdx.x * 256 + threadIdx.x;
    if (idx < 16 * RE_KS * 64) {                       // 9216 Re groups
        int nf = idx / (RE_KS * 64);
        int rem = idx - nf * (RE_KS * 64);
        int ks = rem >> 6, l = rem & 63;
        int f = nf * 16 + (l & 15);
        int k = ks * 32 + ((l >> 4) << 3);
        u16* dh = wsb + OFF_REH + (size_t)idx * 8;
        u16* dl = wsb + OFF_REL + (size_t)idx * 8;
        #pragma unroll
        for (int e = 0; e < 8; ++e) {
            int kk = k + e;
            float x = (kk <= 256) ? dftr[(size_t)f * PW + kk] : 0.f;
            u16 h = f2bf(x);
            dh[e] = h;
            dl[e] = f2bf(x - bf2f(h));
        }
    } else if (idx < 16 * RE_KS * 64 + 16 * IM_KS * 64) {   // 8192 Im groups
        int j = idx - 16 * RE_KS * 64;
        int nf = j / (IM_KS * 64);
        int rem = j - nf * (IM_KS * 64);
        int ks = rem >> 6, l = rem & 63;
        int f = nf * 16 + (l & 15);
        int k = ks * 32 + ((l >> 4) << 3);
        u16* dh = wsb + OFF_IMH + (size_t)j * 8;
        u16* dl = wsb + OFF_IML + (size_t)j * 8;
        #pragma unroll
        for (int e = 0; e < 8; ++e) {
            float x = dfti[(size_t)f * PW + k + e];    // k+e <= 255
            u16 h = f2bf(x);
            dh[e] = h;
            dl[e] = f2bf(x - bf2f(h));
        }
    } else {                                            // mel groups
        int m = idx - (16 * RE_KS * 64 + 16 * IM_KS * 64);
        if (m < 6 * 8 * 64) {
            int nf = m / (8 * 64);
            int ks = (m >> 6) & 7, l = m & 63;
            int n = nf * 16 + (l & 15);
            int k = ks * 32 + ((l >> 4) << 3);
            u16* dst = wsb + OFF_MEL + (size_t)m * 8;
            #pragma unroll
            for (int e = 0; e < 8; ++e)
                dst[e] = (n < NM) ? f2bf(melw[(size_t)n * 257 + k + e]) : (u16)0;
        }
    }
}

// ---------------- prep C/S: one wave per bin (512 waves) ----------------
__global__ void prep_cs_kernel(const float* __restrict__ dftr, const float* __restrict__ dfti,
                               const float* __restrict__ win, u16* __restrict__ wsb) {
    const int gw = (blockIdx.x * 256 + threadIdx.x) >> 6;   // 0..511
    const int lane = threadIdx.x & 63;
    float* cs = (float*)(wsb + OFF_CS);
    float acc = 0.f;
    if (gw < 256) {
        const int f = gw;
        for (int t = lane; t <= 256; t += 64) {
            float wt = (t < FL) ? win[t] : 0.f;
            float wu = (t >= 1 && t < 256 && (512 - t) < FL) ? win[512 - t] : 0.f;
            acc += (wt + wu) * dftr[(size_t)f * PW + t];
        }
    } else {
        const int ff = gw - 256;
        for (int t = lane; t <= 255; t += 64) {
            float wt = (t < FL) ? win[t] : 0.f;
            float wu = (t >= 1 && (512 - t) < FL) ? win[512 - t] : 0.f;
            acc += (wt - wu) * dfti[(size_t)ff * PW + t];
        }
    }
    #pragma unroll
    for (int o = 32; o; o >>= 1) acc += __shfl_xor(acc, o);
    if (lane == 0) cs[gw] = acc;
}

// swizzle select: 0 -> (r&7)<<4 (512-B stride), 1 -> ((r>>1)&3)<<4 (320-B), 2 -> none (272-B)
__device__ __forceinline__ u32 swz(int SWT, u32 r) {
    return (SWT == 0) ? ((r & 7u) << 4) : (SWT == 1) ? (((r >> 1) & 3u) << 4) : 0u;
}

// 9 MFMA for one (bh,bl) ping-pong slot: 3 m-frags x 3 split-product terms
#define MFMA9(D, J)                                                                        \
    _Pragma("unroll")                                                                      \
    for (int mf = 0; mf < 3; ++mf) {                                                       \
        acc[mf][J] = __builtin_amdgcn_mfma_f32_16x16x32_bf16(aH[mf], D[0], acc[mf][J], 0, 0, 0); \
        acc[mf][J] = __builtin_amdgcn_mfma_f32_16x16x32_bf16(aL[mf], D[0], acc[mf][J], 0, 0, 0); \
        acc[mf][J] = __builtin_amdgcn_mfma_f32_16x16x32_bf16(aH[mf], D[1], acc[mf][J], 0, 0, 0); \
    }

// ---------------- DFT pass: 3 m-frags, 2 n-frags, B ping-pong prefetch ----------------
template<int RS, int SWT, int NKS, int BKS>
__device__ __forceinline__ void dft_pass3(
    const char* tH, const char* tL,
    const u16* __restrict__ bH, const u16* __restrict__ bL,
    int ks0, int w, int lane, f32x4 (&acc)[3][2]) {

    bf16x8 aH[3], aL[3], Ba[2], Bb[2];

#define LDA_P(KS)                                                              \
    { _Pragma("unroll")                                                        \
      for (int mf = 0; mf < 3; ++mf) {                                         \
        u32 r = (u32)(mf * 16 + (lane & 15));                                  \
        u32 off = (u32)((KS) * 64 + ((lane >> 4) << 4));                       \
        u32 byte = r * RS + (off ^ swz(SWT, r));                               \
        aH[mf] = *(const bf16x8*)(tH + byte);                                  \
        aL[mf] = *(const bf16x8*)(tL + byte);                                  \
      } }
#define LDB_P(KSG, J, D)                                                       \
    {                                                                          \
        size_t o = ((size_t)((2 * w + (J)) * BKS + (KSG)) * 64 + lane) * 8;    \
        D[0] = *(const bf16x8*)(bH + o);                                       \
        D[1] = *(const bf16x8*)(bL + o);                                       \
    }

    LDB_P(ks0, 0, Ba);
    #pragma unroll
    for (int ks = 0; ks < NKS; ++ks) {
        LDA_P(ks);
        LDB_P(ks0 + ks, 1, Bb);
        MFMA9(Ba, 0);
        if (ks + 1 < NKS) LDB_P(ks0 + ks + 1, 0, Ba);
        MFMA9(Bb, 1);
    }
#undef LDA_P
#undef LDB_P
}

__device__ __forceinline__ void pack_write(const float* ys, char* baseH, char* baseL, u32 byte) {
    u32x4 hv, lv;
    #pragma unroll
    for (int e = 0; e < 4; ++e) {
        float y0 = ys[2 * e], y1 = ys[2 * e + 1];
        u32 h = cvtpk2(y0, y1);
        hv[e] = h;
        float h0 = __builtin_bit_cast(float, h << 16);
        float h1 = __builtin_bit_cast(float, h & 0xFFFF0000u);
        lv[e] = cvtpk2(y0 - h0, y1 - h1);
    }
    *(u32x4*)(baseH + byte) = hv;
    *(u32x4*)(baseL + byte) = lv;
}

// ---------------- pack one frame row, chunk0 (t 0..127 + fold 385..399) ----------------
__device__ __forceinline__ float pack_c0(const float* wb, const float4* win4,
                                         const float* win, char* T,
                                         int f0, int rr, int lane, int cg) {
    const int fr = f0 + rr;
    const bool valid = fr < NFRAMES;
    const float* x = wb + (size_t)fr * FS;
    const float4* x4 = (const float4*)x;
    float ps = 0.f;

    float4 v0 = {0,0,0,0}, v1 = {0,0,0,0};
    if (valid) { v0 = x4[2 * cg]; v1 = x4[2 * cg + 1]; }
    ps += v0.x + v0.y + v0.z + v0.w + v1.x + v1.y + v1.z + v1.w;
    float4 w0 = win4[2 * cg], w1 = win4[2 * cg + 1];
    float xpn = __shfl(v1.w, lane - 1);
    float xprev = (cg == 0) ? v0.x : xpn;
    float y[8];
    y[0] = (v0.x - PRE * xprev) * w0.x;
    y[1] = (v0.y - PRE * v0.x) * w0.y;
    y[2] = (v0.z - PRE * v0.y) * w0.z;
    y[3] = (v0.w - PRE * v0.z) * w0.w;
    y[4] = (v1.x - PRE * v0.w) * w1.x;
    y[5] = (v1.y - PRE * v1.x) * w1.y;
    y[6] = (v1.z - PRE * v1.y) * w1.z;
    y[7] = (v1.w - PRE * v1.z) * w1.w;

    float yr[8];
    #pragma unroll
    for (int e = 0; e < 8; ++e) yr[e] = 0.f;
    if (cg >= 14) {                      // u = 512-t in 385..399
        const int u0 = 512 - 8 * cg;     // 400 (cg14) or 392 (cg15)
        float4 xr0 = {0,0,0,0}, xr1 = {0,0,0,0};
        float xu0 = 0.f;
        if (valid) {
            xr0 = x4[u0 / 4 - 2]; xr1 = x4[u0 / 4 - 1];
            if (u0 <= 399) xu0 = x[u0];
        }
        ps += xr0.x + xr0.y + xr0.z + xr0.w + xr1.x + xr1.y + xr1.z + xr1.w;
        float4 wr0 = win4[u0 / 4 - 2], wr1 = win4[u0 / 4 - 1];
        float wu0 = (u0 <= 399) ? win[u0] : 0.f;
        yr[0] = (xu0   - PRE * xr1.w) * wu0;
        yr[1] = (xr1.w - PRE * xr1.z) * wr1.w;
        yr[2] = (xr1.z - PRE * xr1.y) * wr1.z;
        yr[3] = (xr1.y - PRE * xr1.x) * wr1.y;
        yr[4] = (xr1.x - PRE * xr0.w) * wr1.x;
        yr[5] = (xr0.w - PRE * xr0.z) * wr0.w;
        yr[6] = (xr0.z - PRE * xr0.y) * wr0.z;
        yr[7] = (xr0.y - PRE * xr0.x) * wr0.y;
    }
    float s8[8], d8[8];
    #pragma unroll
    for (int e = 0; e < 8; ++e) { s8[e] = y[e] + yr[e]; d8[e] = y[e] - yr[e]; }
    u32 byte = (u32)rr * 272u + (u32)cg * 16u;
    pack_write(s8, T + C0_SH, T + C0_SL, byte);
    pack_write(d8, T + C0_DH, T + C0_DL, byte);
    return ps;
}

// ---------------- pack one frame row, chunk1 (t 128..255 + fold 256..384) ----------------
__device__ __forceinline__ float pack_c1(const float* wb, const float4* win4,
                                         const float* win, char* T,
                                         int f0, int rr, int lane, int cg) {
    const int fr = f0 + rr;
    const bool valid = fr < NFRAMES;
    const float* x = wb + (size_t)fr * FS;
    const float4* x4 = (const float4*)x;
    float ps = 0.f;

    float4 v0 = {0,0,0,0}, v1 = {0,0,0,0};
    if (valid) { v0 = x4[32 + 2 * cg]; v1 = x4[33 + 2 * cg]; }
    ps += v0.x + v0.y + v0.z + v0.w + v1.x + v1.y + v1.z + v1.w;
    float4 w0 = win4[32 + 2 * cg], w1 = win4[33 + 2 * cg];
    float xpn = __shfl(v1.w, lane - 1);
    float xprev = (cg == 0) ? (valid ? x[127] : 0.f) : xpn;
    float y[8];
    y[0] = (v0.x - PRE * xprev) * w0.x;
    y[1] = (v0.y - PRE * v0.x) * w0.y;
    y[2] = (v0.z - PRE * v0.y) * w0.z;
    y[3] = (v0.w - PRE * v0.z) * w0.w;
    y[4] = (v1.x - PRE * v0.w) * w1.x;
    y[5] = (v1.y - PRE * v1.x) * w1.y;
    y[6] = (v1.z - PRE * v1.y) * w1.z;
    y[7] = (v1.w - PRE * v1.z) * w1.w;

    const int u0 = 384 - 8 * cg;        // 264..384, all fold
    float4 xr0 = {0,0,0,0}, xr1 = {0,0,0,0};
    float xu0 = 0.f;
    if (valid) { xr0 = x4[u0 / 4 - 2]; xr1 = x4[u0 / 4 - 1]; xu0 = x[u0]; }
    ps += xr0.x + xr0.y + xr0.z + xr0.w + xr1.x + xr1.y + xr1.z + xr1.w;
    float4 wr0 = win4[u0 / 4 - 2], wr1 = win4[u0 / 4 - 1];
    float wu0 = win[u0];
    float yr[8];
    yr[0] = (xu0   - PRE * xr1.w) * wu0;
    yr[1] = (xr1.w - PRE * xr1.z) * wr1.w;
    yr[2] = (xr1.z - PRE * xr1.y) * wr1.z;
    yr[3] = (xr1.y - PRE * xr1.x) * wr1.y;
    yr[4] = (xr1.x - PRE * xr0.w) * wr1.x;
    yr[5] = (xr0.w - PRE * xr0.z) * wr0.w;
    yr[6] = (xr0.z - PRE * xr0.y) * wr0.z;
    yr[7] = (xr0.y - PRE * xr0.x) * wr0.y;

    float s8[8], d8[8];
    #pragma unroll
    for (int e = 0; e < 8; ++e) { s8[e] = y[e] + yr[e]; d8[e] = y[e] - yr[e]; }
    u32 byteS = (u32)rr * 320u + (((u32)cg * 16u) ^ ((((u32)rr >> 1) & 3u) << 4));
    u32 byteD = (u32)rr * 272u + (u32)cg * 16u;
    pack_write(s8, T + C1_SH, T + C1_SL, byteS);
    pack_write(d8, T + C1_DH, T + C1_DL, byteD);
    return ps;
}

// ---------------- main fused kernel (512 threads / 8 waves, MT=48) ----------------
__global__ __launch_bounds__(512, 4) void fbank_mfma(
    const float* __restrict__ wave, const float* __restrict__ win,
    const u16* __restrict__ wsb, float* __restrict__ out) {
    __shared__ float smean[MT];
    __shared__ u16 stile[28416];       // 56,832 B tile buffer (power overlay fits)
    char* T = (char*)stile;

    const int tid = threadIdx.x, w = tid >> 6, lane = tid & 63;
    const int q = lane >> 4;           // frame sub-row within wave
    const int cg = lane & 15;          // col-group
    const int b = blockIdx.y;
    const int f0 = blockIdx.x * MT;
    const float* wb = wave + (size_t)b * TLEN;
    const float4* win4 = (const float4*)win;

    const int rrA = w * 4 + q;         // rows 0..31 (all waves)
    const int rrB = 32 + rrA;          // rows 32..47 (waves 0..3 only)

    // ---- P1b: chunk0 packs ----
    float psA = pack_c0(wb, win4, win, T, f0, rrA, lane, cg);
    float psB = 0.f;
    if (w < 4) psB = pack_c0(wb, win4, win, T, f0, rrB, lane, cg);
    __syncthreads();

    // ---- GEMM chunk0: RE ks 0..3 (A=s), IM ks 0..3 (A=d); wave w: bins 32w.. ----
    f32x4 accR[3][2], accI[3][2];
    #pragma unroll
    for (int mf = 0; mf < 3; ++mf)
        #pragma unroll
        for (int j = 0; j < 2; ++j) { accR[mf][j] = (f32x4)0.f; accI[mf][j] = (f32x4)0.f; }

    dft_pass3<272, 2, 4, RE_KS>(T + C0_SH, T + C0_SL, wsb + OFF_REH, wsb + OFF_REL, 0, w, lane, accR);
    dft_pass3<272, 2, 4, IM_KS>(T + C0_DH, T + C0_DL, wsb + OFF_IMH, wsb + OFF_IML, 0, w, lane, accI);
    __syncthreads();

    // ---- P1c: chunk1 packs + mean finalize + s tail ----
    psA += pack_c1(wb, win4, win, T, f0, rrA, lane, cg);
    if (w < 4) psB += pack_c1(wb, win4, win, T, f0, rrB, lane, cg);
    {
        float a = psA;
        #pragma unroll
        for (int o = 8; o; o >>= 1) a += __shfl_xor(a, o);
        if (cg == 0) smean[rrA] = a * (1.0f / FL);
    }
    if (w < 4) {
        float a = psB;
        #pragma unroll
        for (int o = 8; o; o >>= 1) a += __shfl_xor(a, o);
        if (cg == 0) smean[rrB] = a * (1.0f / FL);
    }
    // s tail: cols t=256..287 (units 16..19): only t=256 nonzero (x-only)
    if (w < 4 && lane < MT) {
        const int trr = lane;
        const int tfr = f0 + trr;
        float y256 = 0.f;
        if (w == 0 && tfr < NFRAMES) {
            const float* tx = wb + (size_t)tfr * FS;
            y256 = (tx[256] - PRE * tx[255]) * win[256];
        }
        float s8[8] = {y256, 0.f, 0.f, 0.f, 0.f, 0.f, 0.f, 0.f};
        u32 byte = (u32)trr * 320u + ((((u32)(16 + w)) * 16u) ^ ((((u32)trr >> 1) & 3u) << 4));
        pack_write(s8, T + C1_SH, T + C1_SL, byte);
    }
    __syncthreads();

    // ---- GEMM chunk1: RE ks 4..8 (RS320 SWT1), IM ks 4..7 (RS272) ----
    dft_pass3<320, 1, 5, RE_KS>(T + C1_SH, T + C1_SL, wsb + OFF_REH, wsb + OFF_REL, 4, w, lane, accR);
    dft_pass3<272, 2, 4, IM_KS>(T + C1_DH, T + C1_DL, wsb + OFF_IMH, wsb + OFF_IML, 4, w, lane, accI);
    __syncthreads();

    // ---- power with mean correction -> LDS bf16 [48][256] (512-B stride) ----
    {
        const float* cs = (const float*)(wsb + OFF_CS);
        #pragma unroll
        for (int mf = 0; mf < 3; ++mf)
            #pragma unroll
            for (int j = 0; j < 2; ++j) {
                const u32 bin = (u32)(32 * w + j * 16 + cg);
                const float Cb = cs[bin], Sb = cs[256 + bin];
                #pragma unroll
                for (int r = 0; r < 4; ++r) {
                    u32 row = (u32)(mf * 16 + (q << 2) + r);
                    const float mcr = (1.0f - PRE) * smean[row];
                    float pR = accR[mf][j][r] - mcr * Cb;
                    float pI = accI[mf][j][r] - mcr * Sb;
                    float pw = pR * pR + pI * pI;
                    u32 byte = (row * 512u + bin * 2u) ^ ((row & 7u) << 4);
                    *(u16*)(T + byte) = f2bf(pw);
                }
            }
    }
    __syncthreads();

    // ---- mel GEMM (M=48, N=96 padded, K=256): 6 combos on waves 0..5 ----
    const u16* melb = wsb + OFF_MEL;
    if (w < 6) {
        const int mfm = w >> 1;            // row-group 0..2 (rows mfm*16..+15)
        const int nf0 = (w & 1) * 3;       // frag trio {0,1,2} or {3,4,5(pad)}
        f32x4 accM[3];
        #pragma unroll
        for (int j = 0; j < 3; ++j) accM[j] = (f32x4)0.f;
        for (int ks = 0; ks < 8; ++ks) {
            u32 row = (u32)(mfm * 16 + cg);
            u32 byte = (row * 512u + (u32)(ks * 32 + (q << 3)) * 2u) ^ ((row & 7u) << 4);
            bf16x8 aP = *(const bf16x8*)(T + byte);
            #pragma unroll
            for (int j = 0; j < 3; ++j) {
                bf16x8 bM = *(const bf16x8*)(melb + ((size_t)((nf0 + j) * 8 + ks) * 64 + lane) * 8);
                accM[j] = __builtin_amdgcn_mfma_f32_16x16x32_bf16(aP, bM, accM[j], 0, 0, 0);
            }
        }
        #pragma unroll
        for (int j = 0; j < 3; ++j) {
            const int m = (nf0 + j) * 16 + cg;
            #pragma unroll
            for (int r = 0; r < 4; ++r) {
                const int rowl = mfm * 16 + (q << 2) + r;
                const int ofr = f0 + rowl;
                if (ofr < NFRAMES && m < NM) {
                    float v = fmaxf(accM[j][r] + EPSF, EPSF);
                    out[((size_t)b * NFRAMES + ofr) * NM + m] = logf(v);
                }
            }
        }
    }
}

// ---------------- fallback (fp32 kernel, used if ws too small) ----------------
#define TFB 16
#define NB 256
__global__ __launch_bounds__(256, 3) void fbank_fallback(
    const float* __restrict__ wave, const float* __restrict__ win,
    const float* __restrict__ dftr, const float* __restrict__ dfti,
    const float* __restrict__ melw, float* __restrict__ out) {
    __shared__ float s_fr[TFB][PW];
    __shared__ float s_pw[TFB][NB + 1];
    const int tid = threadIdx.x, wv = tid >> 6, lane = tid & 63;
    const int fbase = blockIdx.x * TFB;
    #pragma unroll
    for (int j = 0; j < TFB / 4; ++j) {
        const int lf = wv * (TFB / 4) + j;
        const int gid = fbase + lf;
        const int bb = gid / NFRAMES;
        const int fr = gid - bb * NFRAMES;
        const float* x = wave + (size_t)bb * TLEN + (size_t)fr * FS;
        float s = 0.f;
        for (int i = lane; i < FL; i += 64) s += x[i];
        #pragma unroll
        for (int off = 32; off >= 1; off >>= 1) s += __shfl_xor(s, off);
        const float mean = s * (1.0f / FL);
        for (int i = lane; i < FL; i += 64) {
            const float xi = x[i];
            const float xm = (i == 0) ? xi : x[i - 1];
            s_fr[lf][i] = (xi - PRE * xm - (1.0f - PRE) * mean) * win[i];
        }
        for (int i = FL + lane; i < PW; i += 64) s_fr[lf][i] = 0.f;
    }
    __syncthreads();
    {
        const int bin = tid;
        const float4* dr4 = (const float4*)(dftr + (size_t)bin * PW);
        const float4* di4 = (const float4*)(dfti + (size_t)bin * PW);
        float accr[TFB], acci[TFB];
        #pragma unroll
        for (int f = 0; f < TFB; ++f) { accr[f] = 0.f; acci[f] = 0.f; }
        for (int k4 = 0; k4 < PW / 4; ++k4) {
            const float4 r = dr4[k4], im = di4[k4];
            #pragma unroll
            for (int f = 0; f < TFB; ++f) {
                const float4 fr = *(const float4*)&s_fr[f][k4 * 4];
                accr[f] += fr.x * r.x + fr.y * r.y + fr.z * r.z + fr.w * r.w;
                acci[f] += fr.x * im.x + fr.y * im.y + fr.z * im.z + fr.w * im.w;
            }
        }
        #pragma unroll
        for (int f = 0; f < TFB; ++f) s_pw[f][bin] = accr[f] * accr[f] + acci[f] * acci[f];
    }
    __syncthreads();
    for (int o = tid; o < TFB * NM; o += 256) {
        const int f = o / NM, m = o - f * NM;
        const float* wm = melw + (size_t)m * 257;
        float acc = 0.f;
        for (int k = 0; k < NB; ++k) acc += s_pw[f][k] * wm[k];
        out[(size_t)(fbase + f) * NM + m] = logf(fmaxf(acc + EPSF, EPSF));
    }
}

extern "C" void kernel_launch(void* const* d_in, const int* in_sizes, int n_in,
                              void* d_out, int out_size, void* d_ws, size_t ws_size,
                              hipStream_t stream) {
    const float* wave = (const float*)d_in[0];
    const float* win  = (const float*)d_in[1];
    const float* dftr = (const float*)d_in[2];
    const float* dfti = (const float*)d_in[3];
    const float* melw = (const float*)d_in[4];
    float* out = (float*)d_out;

    if (ws_size >= WS_NEED) {
        u16* wsb = (u16*)d_ws;
        const int prep_threads = 16 * RE_KS * 64 + 16 * IM_KS * 64 + 6 * 8 * 64;  // 20480
        prep_kernel<<<(prep_threads + 255) / 256, 256, 0, stream>>>(dftr, dfti, melw, wsb);
        prep_cs_kernel<<<128, 256, 0, stream>>>(dftr, dfti, win, wsb);   // 512 waves, 1/bin
        dim3 grid(NTILES, BATCH);
        fbank_mfma<<<grid, 512, 0, stream>>>(wave, win, wsb, out);
    } else {
        const int nblocks = (BATCH * NFRAMES) / TFB;
        fbank_fallback<<<nblocks, 256, 0, stream>>>(wave, win, dftr, dfti, melw, out);
    }
}